// Round 5
// baseline (1452.254 us; speedup 1.0000x reference)
//
#include <hip/hip_runtime.h>
#include <math.h>

#define NQd 100
#define BSd 8
#define NPTd 17
#define DIMd 256
#define NHd 8
#define DHd 32
#define LVLd 4
#define PTd 4
#define DFFd 1024
#define NTOK (NQd*BSd*NPTd)        // 13600
#define LENIN 11253
#define MTOK (BSd*LENIN)           // 90024

// ---------------------------------------------------------------------------
// Generic fp32 GEMM: C[m][col0+n] = act(A[m][:K] . W[n][:K] + bias[n])
// block tile 64x64, 16x16 threads, 4x4 per thread (strided), K-chunk 16
// ---------------------------------------------------------------------------
template<bool RELU>
__global__ void gemm_bias(const float* __restrict__ A, const float* __restrict__ W,
                          const float* __restrict__ bias, float* __restrict__ C,
                          int M, int N, int K, int ldc, int col0) {
    __shared__ float As[16][65];
    __shared__ float Bs[16][65];
    const int tx = threadIdx.x, ty = threadIdx.y;
    const int tid = ty * 16 + tx;
    const int m0 = blockIdx.y * 64, n0 = blockIdx.x * 64;
    float acc[4][4] = {};
    const int ml = tid >> 2;         // 0..63
    const int kl = (tid & 3) * 4;    // 0,4,8,12
    for (int k0 = 0; k0 < K; k0 += 16) {
        float4 va = make_float4(0.f, 0.f, 0.f, 0.f);
        int gm = m0 + ml;
        if (gm < M) va = *reinterpret_cast<const float4*>(&A[(size_t)gm * K + k0 + kl]);
        As[kl + 0][ml] = va.x; As[kl + 1][ml] = va.y;
        As[kl + 2][ml] = va.z; As[kl + 3][ml] = va.w;
        int gn = n0 + ml;
        float4 vb = *reinterpret_cast<const float4*>(&W[(size_t)gn * K + k0 + kl]);
        Bs[kl + 0][ml] = vb.x; Bs[kl + 1][ml] = vb.y;
        Bs[kl + 2][ml] = vb.z; Bs[kl + 3][ml] = vb.w;
        __syncthreads();
#pragma unroll
        for (int kk = 0; kk < 16; ++kk) {
            float a[4], b[4];
#pragma unroll
            for (int i = 0; i < 4; ++i) a[i] = As[kk][ty + 16 * i];
#pragma unroll
            for (int j = 0; j < 4; ++j) b[j] = Bs[kk][tx + 16 * j];
#pragma unroll
            for (int i = 0; i < 4; ++i)
#pragma unroll
                for (int j = 0; j < 4; ++j) acc[i][j] += a[i] * b[j];
        }
        __syncthreads();
    }
#pragma unroll
    for (int i = 0; i < 4; ++i) {
        int gm = m0 + ty + 16 * i;
        if (gm >= M) continue;
#pragma unroll
        for (int j = 0; j < 4; ++j) {
            int nl = tx + 16 * j;
            float v = acc[i][j] + bias[n0 + nl];
            if (RELU) v = fmaxf(v, 0.f);
            C[(size_t)gm * ldc + col0 + n0 + nl] = v;
        }
    }
}

// ---------------------------------------------------------------------------
// Row gather (+optional add) into a contiguous (t, 256) buffer.
// mode 0: r=t (qk = tgt+qpos)    mode 1: y-order from x    mode 2: deform q order
// ---------------------------------------------------------------------------
__global__ void gather_rows(const float* __restrict__ src, const float* __restrict__ add,
                            float* __restrict__ dst, int mode) {
    int t = blockIdx.x, c = threadIdx.x;
    int r;
    if (mode == 0) r = t;
    else if (mode == 1) { int m = t / 100, q = t % 100; r = q * 136 + m; }
    else { int b = t / 1700, jj = t % 1700; int q = jj / 17, p = jj % 17; r = q * 136 + b * 17 + p; }
    float v = src[(size_t)r * 256 + c];
    if (add) v += add[(size_t)r * 256 + c];
    dst[(size_t)t * 256 + c] = v;
}

// ---------------------------------------------------------------------------
// MHA S=17 (group attention). qkv rows: t*768 (Q|K|V). block=(group, head)
// ---------------------------------------------------------------------------
__global__ void attn17(const float* __restrict__ qkv, float* __restrict__ out) {
    const int g = blockIdx.x, h = blockIdx.y;
    __shared__ float q[17][32], k[17][32], v[17][32], s[17][18];
    const int tid = threadIdx.x;  // 256
    for (int idx = tid; idx < 17 * 32; idx += 256) {
        int i = idx >> 5, d = idx & 31;
        size_t row = (size_t)(g * 17 + i) * 768 + h * 32 + d;
        q[i][d] = qkv[row];
        k[i][d] = qkv[row + 256];
        v[i][d] = qkv[row + 512];
    }
    __syncthreads();
    for (int idx = tid; idx < 17 * 17; idx += 256) {
        int i = idx / 17, j = idx % 17;
        float acc = 0.f;
#pragma unroll
        for (int d = 0; d < 32; ++d) acc += q[i][d] * k[j][d];
        s[i][j] = acc * 0.17677669529663688f;
    }
    __syncthreads();
    if (tid < 17) {
        float m = -1e30f;
        for (int j = 0; j < 17; ++j) m = fmaxf(m, s[tid][j]);
        float sum = 0.f;
        for (int j = 0; j < 17; ++j) { float e = expf(s[tid][j] - m); s[tid][j] = e; sum += e; }
        float inv = 1.f / sum;
        for (int j = 0; j < 17; ++j) s[tid][j] *= inv;
    }
    __syncthreads();
    for (int idx = tid; idx < 17 * 32; idx += 256) {
        int i = idx >> 5, d = idx & 31;
        float acc = 0.f;
        for (int j = 0; j < 17; ++j) acc += s[i][j] * v[j][d];
        out[(size_t)(g * 17 + i) * 256 + h * 32 + d] = acc;
    }
}

// ---------------------------------------------------------------------------
// MHA S=100 (query attention). 128 threads, block=(group b' in 136, head)
// ---------------------------------------------------------------------------
__global__ void attn100(const float* __restrict__ qkv, float* __restrict__ out) {
    const int g = blockIdx.x, h = blockIdx.y;
    __shared__ float K[100][32], V[100][32];
    __shared__ float qv[32];
    __shared__ float s[100];
    __shared__ float red[128];
    const int tid = threadIdx.x;  // 128
    for (int idx = tid; idx < 100 * 32; idx += 128) {
        int j = idx >> 5, d = idx & 31;
        size_t row = (size_t)(g * 100 + j) * 768 + h * 32 + d;
        K[j][d] = qkv[row + 256];
        V[j][d] = qkv[row + 512];
    }
    __syncthreads();
    const int d = tid & 31, part = tid >> 5;
    for (int i = 0; i < 100; ++i) {
        if (tid < 32) qv[tid] = qkv[(size_t)(g * 100 + i) * 768 + h * 32 + tid];
        __syncthreads();
        if (tid < 100) {
            float acc = 0.f;
#pragma unroll
            for (int dd = 0; dd < 32; ++dd) acc += qv[dd] * K[tid][dd];
            s[tid] = acc * 0.17677669529663688f;
        }
        __syncthreads();
        red[tid] = (tid < 100) ? s[tid] : -1e30f;
        __syncthreads();
        for (int st = 64; st > 0; st >>= 1) {
            if (tid < st) red[tid] = fmaxf(red[tid], red[tid + st]);
            __syncthreads();
        }
        float mx = red[0];
        __syncthreads();
        if (tid < 100) s[tid] = expf(s[tid] - mx);
        __syncthreads();
        red[tid] = (tid < 100) ? s[tid] : 0.f;
        __syncthreads();
        for (int st = 64; st > 0; st >>= 1) {
            if (tid < st) red[tid] += red[tid + st];
            __syncthreads();
        }
        float inv = 1.f / red[0];
        __syncthreads();
        float acc = 0.f;
        for (int j = part; j < 100; j += 4) acc += s[j] * V[j][d];
        red[tid] = acc;
        __syncthreads();
        if (tid < 32) {
            float o = (red[tid] + red[tid + 32] + red[tid + 64] + red[tid + 96]) * inv;
            out[(size_t)(g * 100 + i) * 256 + h * 32 + tid] = o;
        }
        __syncthreads();
    }
}

// ---------------------------------------------------------------------------
// Deformable sampling: block per (b, j) token; thread = (h, dh)
// ---------------------------------------------------------------------------
__global__ void deform_sample(const float* __restrict__ value, const float* __restrict__ off,
                              const float* __restrict__ aw, const float* __restrict__ ref,
                              float* __restrict__ out) {
    const int t = blockIdx.x;
    const int b = t / 1700, jj = t % 1700;
    const int q = jj / 17, p = jj % 17;
    const int tid = threadIdx.x;  // 256
    const int h = tid >> 5, d = tid & 31;
    __shared__ float w_s[8][16];
    __shared__ float raw[128];
    if (tid < 128) raw[tid] = aw[(size_t)t * 128 + tid];
    __syncthreads();
    if (tid < 8) {
        float m = -1e30f;
        for (int i = 0; i < 16; ++i) m = fmaxf(m, raw[tid * 16 + i]);
        float sum = 0.f;
        for (int i = 0; i < 16; ++i) { float e = expf(raw[tid * 16 + i] - m); w_s[tid][i] = e; sum += e; }
        float inv = 1.f / sum;
        for (int i = 0; i < 16; ++i) w_s[tid][i] *= inv;
    }
    __syncthreads();
    const int Hs[4] = {92, 46, 23, 12};
    const int Sts[4] = {0, 8464, 10580, 11109};
    const float* refp = ref + (size_t)((q * 8 + b) * 17 + p) * 8;  // L*2
    const float* vb = value + (size_t)b * LENIN * 256 + h * 32 + d;
    const float* offp = off + (size_t)t * 256;
    float acc = 0.f;
#pragma unroll
    for (int l = 0; l < 4; ++l) {
        const int HW = Hs[l];          // square levels
        const float HWf = (float)HW;
        const float rx = refp[l * 2 + 0], ry = refp[l * 2 + 1];
        const int vbase = Sts[l];
#pragma unroll
        for (int pp = 0; pp < 4; ++pp) {
            int oidx = ((h * 4 + l) * 4 + pp) * 2;
            float lx = rx + offp[oidx] / HWf;
            float ly = ry + offp[oidx + 1] / HWf;
            float x = lx * HWf - 0.5f;
            float y = ly * HWf - 0.5f;
            float x0 = floorf(x), y0 = floorf(y);
            float wx = x - x0, wy = y - y0;
            int xi = (int)x0, yi = (int)y0;
            float wgt = w_s[h][l * 4 + pp];
            float sacc = 0.f;
#pragma unroll
            for (int ty = 0; ty < 2; ++ty) {
#pragma unroll
                for (int tx = 0; tx < 2; ++tx) {
                    int yy = yi + ty, xx = xi + tx;
                    bool ok = (xx >= 0) && (xx < HW) && (yy >= 0) && (yy < HW);
                    int yc = min(max(yy, 0), HW - 1);
                    int xc = min(max(xx, 0), HW - 1);
                    float v = vb[(size_t)(vbase + yc * HW + xc) * 256];
                    float w = (ty ? wy : (1.f - wy)) * (tx ? wx : (1.f - wx));
                    sacc += ok ? v * w : 0.f;
                }
            }
            acc += wgt * sacc;
        }
    }
    out[(size_t)t * 256 + h * 32 + d] = acc;
}

// ---------------------------------------------------------------------------
// Residual + LayerNorm over D=256, block per row, with proj-row permutation.
// mode 0: t=r   mode 1: y-order proj   mode 2: deform-order proj
// ---------------------------------------------------------------------------
__global__ void res_ln(const float* __restrict__ res, const float* __restrict__ proj,
                       const float* __restrict__ g, const float* __restrict__ be,
                       float* __restrict__ out, int mode) {
    const int r = blockIdx.x, c = threadIdx.x;
    int t;
    if (mode == 0) t = r;
    else if (mode == 1) { int q = r / 136, m = r % 136; t = m * 100 + q; }
    else { int q = r / 136, rem = r % 136; int b = rem / 17, p = rem % 17; t = b * 1700 + q * 17 + p; }
    float v = res[(size_t)r * 256 + c] + proj[(size_t)t * 256 + c];
    __shared__ float red[256];
    red[c] = v;
    __syncthreads();
    for (int st = 128; st > 0; st >>= 1) {
        if (c < st) red[c] += red[c + st];
        __syncthreads();
    }
    float mean = red[0] * (1.f / 256.f);
    __syncthreads();
    float dv = v - mean;
    red[c] = dv * dv;
    __syncthreads();
    for (int st = 128; st > 0; st >>= 1) {
        if (c < st) red[c] += red[c + st];
        __syncthreads();
    }
    float var = red[0] * (1.f / 256.f);
    out[(size_t)r * 256 + c] = dv * rsqrtf(var + 1e-5f) * g[c] + be[c];
}

// ---------------------------------------------------------------------------
extern "C" void kernel_launch(void* const* d_in, const int* in_sizes, int n_in,
                              void* d_out, int out_size, void* d_ws, size_t ws_size,
                              hipStream_t stream) {
    const float* tgt    = (const float*)d_in[0];
    const float* qpos   = (const float*)d_in[1];
    const float* ref    = (const float*)d_in[2];
    const float* memory = (const float*)d_in[3];
    const float* w_in_w = (const float*)d_in[4];
    const float* b_in_w = (const float*)d_in[5];
    const float* w_out_w= (const float*)d_in[6];
    const float* b_out_w= (const float*)d_in[7];
    const float* w_in_a = (const float*)d_in[8];
    const float* b_in_a = (const float*)d_in[9];
    const float* w_out_a= (const float*)d_in[10];
    const float* b_out_a= (const float*)d_in[11];
    const float* w_off  = (const float*)d_in[12];
    const float* b_off  = (const float*)d_in[13];
    const float* w_aw   = (const float*)d_in[14];
    const float* b_aw   = (const float*)d_in[15];
    const float* w_val  = (const float*)d_in[16];
    const float* b_val  = (const float*)d_in[17];
    const float* w_oc   = (const float*)d_in[18];
    const float* b_oc   = (const float*)d_in[19];
    const float* g_w    = (const float*)d_in[20];
    const float* be_w   = (const float*)d_in[21];
    const float* g_a    = (const float*)d_in[22];
    const float* be_a   = (const float*)d_in[23];
    const float* g1     = (const float*)d_in[24];
    const float* be1    = (const float*)d_in[25];
    const float* g2     = (const float*)d_in[26];
    const float* be2    = (const float*)d_in[27];
    const float* w1     = (const float*)d_in[28];
    const float* b1     = (const float*)d_in[29];
    const float* w2     = (const float*)d_in[30];
    const float* b2     = (const float*)d_in[31];

    float* X  = (float*)d_out;                    // persistent x, 13600x256
    float* ws = (float*)d_ws;
    float* R1 = ws;                               // 23,046,144 (qkv / value / ffn-hidden)
    float* R2 = R1 + (size_t)MTOK * 256;          // 3,481,600  (gemm A input / proj out)
    float* R3 = R2 + (size_t)NTOK * 256;          // 3,481,600  (attn out / deform out)
    float* R5 = R3 + (size_t)NTOK * 256;          // 3,481,600  (offsets)
    float* R6 = R5 + (size_t)NTOK * 256;          // 1,740,800  (attn weights raw)

    dim3 t16(16, 16);
    auto gemm = [&](const float* A, const float* W, const float* b, float* C,
                    int M, int N, int K, int ldc, int col0, bool relu) {
        dim3 grid(N / 64, (M + 63) / 64);
        if (relu) gemm_bias<true><<<grid, t16, 0, stream>>>(A, W, b, C, M, N, K, ldc, col0);
        else      gemm_bias<false><<<grid, t16, 0, stream>>>(A, W, b, C, M, N, K, ldc, col0);
    };

    // ---- Phase 1: group self-attention (S=17) ----
    gather_rows<<<NTOK, 256, 0, stream>>>(tgt, qpos, R2, 0);                 // qk
    gemm(R2, w_in_w, b_in_w, R1, NTOK, 512, 256, 768, 0, false);            // Q,K
    gemm(tgt, w_in_w + 512 * 256, b_in_w + 512, R1, NTOK, 256, 256, 768, 512, false); // V
    attn17<<<dim3(800, 8), 256, 0, stream>>>(R1, R3);
    gemm(R3, w_out_w, b_out_w, R2, NTOK, 256, 256, 256, 0, false);
    res_ln<<<NTOK, 256, 0, stream>>>(tgt, R2, g_w, be_w, X, 0);

    // ---- Phase 2: query self-attention (S=100) ----
    gather_rows<<<NTOK, 256, 0, stream>>>(X, nullptr, R2, 1);                // y
    gemm(R2, w_in_a, b_in_a, R1, NTOK, 768, 256, 768, 0, false);
    attn100<<<dim3(136, 8), 128, 0, stream>>>(R1, R3);
    gemm(R3, w_out_a, b_out_a, R2, NTOK, 256, 256, 256, 0, false);
    res_ln<<<NTOK, 256, 0, stream>>>(X, R2, g_a, be_a, X, 1);

    // ---- Phase 3: deformable attention ----
    gemm(memory, w_val, b_val, R1, MTOK, 256, 256, 256, 0, false);           // value
    gather_rows<<<NTOK, 256, 0, stream>>>(X, qpos, R2, 2);                   // q_d
    gemm(R2, w_off, b_off, R5, NTOK, 256, 256, 256, 0, false);               // offsets
    gemm(R2, w_aw, b_aw, R6, NTOK, 128, 256, 128, 0, false);                 // raw attn w
    deform_sample<<<NTOK, 256, 0, stream>>>(R1, R5, R6, ref, R3);
    gemm(R3, w_oc, b_oc, R2, NTOK, 256, 256, 256, 0, false);
    res_ln<<<NTOK, 256, 0, stream>>>(X, R2, g1, be1, X, 2);

    // ---- Phase 4: FFN ----
    gemm(X, w1, b1, R1, NTOK, 1024, 256, 1024, 0, true);                     // relu
    gemm(R1, w2, b2, R2, NTOK, 256, 1024, 256, 0, false);
    res_ln<<<NTOK, 256, 0, stream>>>(X, R2, g2, be2, X, 0);
}

// Round 6
// 524.214 us; speedup vs baseline: 2.7703x; 2.7703x over previous
//
#include <hip/hip_runtime.h>
#include <hip/hip_bf16.h>
#include <math.h>

#define NQd 100
#define BSd 8
#define NPTd 17
#define DIMd 256
#define NHd 8
#define DHd 32
#define DFFd 1024
#define NTOK (NQd*BSd*NPTd)        // 13600
#define LENIN 11253
#define MTOK (BSd*LENIN)           // 90024

typedef __attribute__((ext_vector_type(8))) short bf16x8;
typedef __attribute__((ext_vector_type(4))) float f32x4;

__device__ inline short f2bs(float f) {
    __hip_bfloat16 h = __float2bfloat16(f);
    return *reinterpret_cast<short*>(&h);
}

// ---------------------------------------------------------------------------
// bf16 MFMA GEMM: C[m][col0+n] = act(A[m][:K] . W[n][:K] + bias[n])
// 128x128 tile, 256 thr (4 waves, 2x2), 4x4 frags of 16x16x32, BK=32.
// LDS row stride 40 bf16 (80 B, odd multiple of 16B -> uniform bank coverage).
// A_FP32: A is fp32, converted during staging. OUT_BF16: C stored as bf16.
// ---------------------------------------------------------------------------
template<bool RELU, bool OUT_BF16, bool A_FP32>
__global__ __launch_bounds__(256)
void gemm_mfma(const void* __restrict__ Av, const __hip_bfloat16* __restrict__ W,
               const float* __restrict__ bias, void* __restrict__ Cv,
               int M, int N, int K, int ldc, int col0) {
    __shared__ __hip_bfloat16 As[128][40];
    __shared__ __hip_bfloat16 Ws[128][40];
    const int tid = threadIdx.x;
    const int lane = tid & 63, wave = tid >> 6;
    const int wr = wave >> 1, wc = wave & 1;
    const int m0 = blockIdx.y * 128, n0 = blockIdx.x * 128;
    const int l15 = lane & 15, lg = lane >> 4;

    f32x4 acc[4][4];
#pragma unroll
    for (int i = 0; i < 4; ++i)
#pragma unroll
        for (int j = 0; j < 4; ++j) acc[i][j] = (f32x4){0.f, 0.f, 0.f, 0.f};

    for (int k0 = 0; k0 < K; k0 += 32) {
        __syncthreads();
#pragma unroll
        for (int it = 0; it < 2; ++it) {
            const int L = tid + it * 256;
            const int row = L >> 2, koct = L & 3;
            // ---- A tile ----
            const int gm = m0 + row;
            bf16x8 av = {0, 0, 0, 0, 0, 0, 0, 0};
            if (A_FP32) {
                if (gm < M) {
                    const float* ap = (const float*)Av + (size_t)gm * K + k0 + koct * 8;
                    float4 f0 = *(const float4*)ap;
                    float4 f1 = *(const float4*)(ap + 4);
                    av = (bf16x8){f2bs(f0.x), f2bs(f0.y), f2bs(f0.z), f2bs(f0.w),
                                  f2bs(f1.x), f2bs(f1.y), f2bs(f1.z), f2bs(f1.w)};
                }
            } else {
                if (gm < M)
                    av = *(const bf16x8*)((const __hip_bfloat16*)Av + (size_t)gm * K + k0 + koct * 8);
            }
            *(bf16x8*)&As[row][koct * 8] = av;
            // ---- W tile (always bf16, always in-bounds: N % 128 == 0) ----
            bf16x8 wv = *(const bf16x8*)(W + (size_t)(n0 + row) * K + k0 + koct * 8);
            *(bf16x8*)&Ws[row][koct * 8] = wv;
        }
        __syncthreads();

        bf16x8 af[4], bfr[4];
#pragma unroll
        for (int f = 0; f < 4; ++f) {
            af[f]  = *(const bf16x8*)&As[wr * 64 + f * 16 + l15][lg * 8];
            bfr[f] = *(const bf16x8*)&Ws[wc * 64 + f * 16 + l15][lg * 8];
        }
#pragma unroll
        for (int fm = 0; fm < 4; ++fm)
#pragma unroll
            for (int fn = 0; fn < 4; ++fn)
                acc[fm][fn] = __builtin_amdgcn_mfma_f32_16x16x32_bf16(af[fm], bfr[fn], acc[fm][fn], 0, 0, 0);
    }

#pragma unroll
    for (int fm = 0; fm < 4; ++fm) {
        const int row = m0 + wr * 64 + fm * 16 + lg * 4;
#pragma unroll
        for (int fn = 0; fn < 4; ++fn) {
            const int coln = n0 + wc * 64 + fn * 16 + l15;
            const float bsv = bias[coln];
#pragma unroll
            for (int r = 0; r < 4; ++r) {
                const int gr = row + r;
                if (gr >= M) continue;
                float v = acc[fm][fn][r] + bsv;
                if (RELU) v = fmaxf(v, 0.f);
                if (OUT_BF16)
                    ((__hip_bfloat16*)Cv)[(size_t)gr * ldc + col0 + coln] = __float2bfloat16(v);
                else
                    ((float*)Cv)[(size_t)gr * ldc + col0 + coln] = v;
            }
        }
    }
}

// ---------------------------------------------------------------------------
// Fused weight conversion fp32 -> bf16 into one packed buffer.
// ---------------------------------------------------------------------------
__global__ void cvt_weights(const float* w0, const float* w1, const float* w2,
                            const float* w3, const float* w4, const float* w5,
                            const float* w6, const float* w7, const float* w8,
                            const float* w9, __hip_bfloat16* dst) {
    int idx = blockIdx.x * 256 + threadIdx.x;
    float v;
    if      (idx <  196608) v = w0[idx];
    else if (idx <  262144) v = w1[idx -  196608];
    else if (idx <  458752) v = w2[idx -  262144];
    else if (idx <  524288) v = w3[idx -  458752];
    else if (idx <  589824) v = w4[idx -  524288];
    else if (idx <  622592) v = w5[idx -  589824];
    else if (idx <  688128) v = w6[idx -  622592];
    else if (idx <  753664) v = w7[idx -  688128];
    else if (idx < 1015808) v = w8[idx -  753664];
    else                    v = w9[idx - 1015808];
    dst[idx] = __float2bfloat16(v);
}

// ---------------------------------------------------------------------------
// Row gather (+optional add) -> contiguous bf16 (t, 256) buffer.
// mode 0: r=t    mode 1: y-order    mode 2: deform q order
// ---------------------------------------------------------------------------
__global__ void gather_rows_b(const float* __restrict__ src, const float* __restrict__ add,
                              __hip_bfloat16* __restrict__ dst, int mode) {
    int t = blockIdx.x, c = threadIdx.x;
    int r;
    if (mode == 0) r = t;
    else if (mode == 1) { int m = t / 100, q = t % 100; r = q * 136 + m; }
    else { int b = t / 1700, jj = t % 1700; int q = jj / 17, p = jj % 17; r = q * 136 + b * 17 + p; }
    float v = src[(size_t)r * 256 + c];
    if (add) v += add[(size_t)r * 256 + c];
    dst[(size_t)t * 256 + c] = __float2bfloat16(v);
}

// ---------------------------------------------------------------------------
// MHA S=17 (group attention). qkv rows: t*768 (Q|K|V). block=(group, head)
// ---------------------------------------------------------------------------
__global__ void attn17(const float* __restrict__ qkv, __hip_bfloat16* __restrict__ out) {
    const int g = blockIdx.x, h = blockIdx.y;
    __shared__ float q[17][32], k[17][32], v[17][32], s[17][18];
    const int tid = threadIdx.x;  // 256
    for (int idx = tid; idx < 17 * 32; idx += 256) {
        int i = idx >> 5, d = idx & 31;
        size_t row = (size_t)(g * 17 + i) * 768 + h * 32 + d;
        q[i][d] = qkv[row];
        k[i][d] = qkv[row + 256];
        v[i][d] = qkv[row + 512];
    }
    __syncthreads();
    for (int idx = tid; idx < 17 * 17; idx += 256) {
        int i = idx / 17, j = idx % 17;
        float acc = 0.f;
#pragma unroll
        for (int d = 0; d < 32; ++d) acc += q[i][d] * k[j][d];
        s[i][j] = acc * 0.17677669529663688f;
    }
    __syncthreads();
    if (tid < 17) {
        float m = -1e30f;
        for (int j = 0; j < 17; ++j) m = fmaxf(m, s[tid][j]);
        float sum = 0.f;
        for (int j = 0; j < 17; ++j) { float e = __expf(s[tid][j] - m); s[tid][j] = e; sum += e; }
        float inv = 1.f / sum;
        for (int j = 0; j < 17; ++j) s[tid][j] *= inv;
    }
    __syncthreads();
    for (int idx = tid; idx < 17 * 32; idx += 256) {
        int i = idx >> 5, d = idx & 31;
        float acc = 0.f;
        for (int j = 0; j < 17; ++j) acc += s[i][j] * v[j][d];
        out[(size_t)(g * 17 + i) * 256 + h * 32 + d] = __float2bfloat16(acc);
    }
}

// ---------------------------------------------------------------------------
// MHA S=100: thread-per-query online softmax. block=(group in 136, head).
// K,V staged in LDS once (1 barrier); K/V reads are wave-uniform broadcasts.
// ---------------------------------------------------------------------------
__global__ __launch_bounds__(128)
void attn100(const float* __restrict__ qkv, __hip_bfloat16* __restrict__ out) {
    const int g = blockIdx.x, h = blockIdx.y;
    __shared__ float Ks[100][32], Vs[100][32];
    const int tid = threadIdx.x;  // 128
    for (int idx = tid; idx < 800; idx += 128) {
        int j = idx >> 3, qd = (idx & 7) * 4;
        const float* base = qkv + (size_t)(g * 100 + j) * 768 + h * 32;
        *(float4*)&Ks[j][qd] = *(const float4*)(base + 256 + qd);
        *(float4*)&Vs[j][qd] = *(const float4*)(base + 512 + qd);
    }
    __syncthreads();
    if (tid >= 100) return;
    const float* qp = qkv + (size_t)(g * 100 + tid) * 768 + h * 32;
    float q[32];
#pragma unroll
    for (int d4 = 0; d4 < 32; d4 += 4) {
        float4 v = *(const float4*)(qp + d4);
        q[d4] = v.x; q[d4 + 1] = v.y; q[d4 + 2] = v.z; q[d4 + 3] = v.w;
    }
    float m = -1e30f, l = 0.f, o[32];
#pragma unroll
    for (int d = 0; d < 32; ++d) o[d] = 0.f;
    for (int j = 0; j < 100; ++j) {
        float s = 0.f;
#pragma unroll
        for (int d = 0; d < 32; ++d) s += q[d] * Ks[j][d];
        s *= 0.17677669529663688f;
        float nm = fmaxf(m, s);
        float f = __expf(m - nm), p = __expf(s - nm);
        l = l * f + p;
#pragma unroll
        for (int d = 0; d < 32; ++d) o[d] = o[d] * f + p * Vs[j][d];
        m = nm;
    }
    float inv = 1.f / l;
    __hip_bfloat16* op = out + (size_t)(g * 100 + tid) * 256 + h * 32;
#pragma unroll
    for (int d = 0; d < 32; ++d) op[d] = __float2bfloat16(o[d] * inv);
}

// ---------------------------------------------------------------------------
// Deformable sampling: block per (b, j) token; thread = (h, dh)
// ---------------------------------------------------------------------------
__global__ void deform_sample(const float* __restrict__ value, const float* __restrict__ off,
                              const float* __restrict__ aw, const float* __restrict__ ref,
                              __hip_bfloat16* __restrict__ out) {
    const int t = blockIdx.x;
    const int b = t / 1700, jj = t % 1700;
    const int q = jj / 17, p = jj % 17;
    const int tid = threadIdx.x;  // 256
    const int h = tid >> 5, d = tid & 31;
    __shared__ float w_s[8][16];
    __shared__ float raw[128];
    if (tid < 128) raw[tid] = aw[(size_t)t * 128 + tid];
    __syncthreads();
    if (tid < 8) {
        float m = -1e30f;
        for (int i = 0; i < 16; ++i) m = fmaxf(m, raw[tid * 16 + i]);
        float sum = 0.f;
        for (int i = 0; i < 16; ++i) { float e = __expf(raw[tid * 16 + i] - m); w_s[tid][i] = e; sum += e; }
        float inv = 1.f / sum;
        for (int i = 0; i < 16; ++i) w_s[tid][i] *= inv;
    }
    __syncthreads();
    const int Hs[4] = {92, 46, 23, 12};
    const int Sts[4] = {0, 8464, 10580, 11109};
    const float* refp = ref + (size_t)((q * 8 + b) * 17 + p) * 8;
    const float* vb = value + (size_t)b * LENIN * 256 + h * 32 + d;
    const float* offp = off + (size_t)t * 256;
    float acc = 0.f;
#pragma unroll
    for (int l = 0; l < 4; ++l) {
        const int HW = Hs[l];
        const float HWf = (float)HW;
        const float rx = refp[l * 2 + 0], ry = refp[l * 2 + 1];
        const int vbase = Sts[l];
#pragma unroll
        for (int pp = 0; pp < 4; ++pp) {
            int oidx = ((h * 4 + l) * 4 + pp) * 2;
            float lx = rx + offp[oidx] / HWf;
            float ly = ry + offp[oidx + 1] / HWf;
            float x = lx * HWf - 0.5f;
            float y = ly * HWf - 0.5f;
            float x0 = floorf(x), y0 = floorf(y);
            float wx = x - x0, wy = y - y0;
            int xi = (int)x0, yi = (int)y0;
            float wgt = w_s[h][l * 4 + pp];
            float sacc = 0.f;
#pragma unroll
            for (int ty = 0; ty < 2; ++ty) {
#pragma unroll
                for (int tx = 0; tx < 2; ++tx) {
                    int yy = yi + ty, xx = xi + tx;
                    bool ok = (xx >= 0) && (xx < HW) && (yy >= 0) && (yy < HW);
                    int yc = min(max(yy, 0), HW - 1);
                    int xc = min(max(xx, 0), HW - 1);
                    float v = vb[(size_t)(vbase + yc * HW + xc) * 256];
                    float w = (ty ? wy : (1.f - wy)) * (tx ? wx : (1.f - wx));
                    sacc += ok ? v * w : 0.f;
                }
            }
            acc += wgt * sacc;
        }
    }
    out[(size_t)t * 256 + h * 32 + d] = __float2bfloat16(acc);
}

// ---------------------------------------------------------------------------
// Residual + LayerNorm over D=256, block per row, proj-row permutation.
// Optional bf16 secondary output (outb).
// ---------------------------------------------------------------------------
__global__ void res_ln(const float* __restrict__ res, const float* __restrict__ proj,
                       const float* __restrict__ g, const float* __restrict__ be,
                       float* __restrict__ out, __hip_bfloat16* __restrict__ outb, int mode) {
    const int r = blockIdx.x, c = threadIdx.x;
    int t;
    if (mode == 0) t = r;
    else if (mode == 1) { int q = r / 136, m = r % 136; t = m * 100 + q; }
    else { int q = r / 136, rem = r % 136; int b = rem / 17, p = rem % 17; t = b * 1700 + q * 17 + p; }
    float v = res[(size_t)r * 256 + c] + proj[(size_t)t * 256 + c];
    __shared__ float red[256];
    red[c] = v;
    __syncthreads();
    for (int st = 128; st > 0; st >>= 1) {
        if (c < st) red[c] += red[c + st];
        __syncthreads();
    }
    float mean = red[0] * (1.f / 256.f);
    __syncthreads();
    float dv = v - mean;
    red[c] = dv * dv;
    __syncthreads();
    for (int st = 128; st > 0; st >>= 1) {
        if (c < st) red[c] += red[c + st];
        __syncthreads();
    }
    float var = red[0] * (1.f / 256.f);
    float o = dv * rsqrtf(var + 1e-5f) * g[c] + be[c];
    out[(size_t)r * 256 + c] = o;
    if (outb) outb[(size_t)r * 256 + c] = __float2bfloat16(o);
}

// ---------------------------------------------------------------------------
extern "C" void kernel_launch(void* const* d_in, const int* in_sizes, int n_in,
                              void* d_out, int out_size, void* d_ws, size_t ws_size,
                              hipStream_t stream) {
    const float* tgt    = (const float*)d_in[0];
    const float* qpos   = (const float*)d_in[1];
    const float* ref    = (const float*)d_in[2];
    const float* memory = (const float*)d_in[3];
    const float* w_in_w = (const float*)d_in[4];
    const float* b_in_w = (const float*)d_in[5];
    const float* w_out_w= (const float*)d_in[6];
    const float* b_out_w= (const float*)d_in[7];
    const float* w_in_a = (const float*)d_in[8];
    const float* b_in_a = (const float*)d_in[9];
    const float* w_out_a= (const float*)d_in[10];
    const float* b_out_a= (const float*)d_in[11];
    const float* w_off  = (const float*)d_in[12];
    const float* b_off  = (const float*)d_in[13];
    const float* w_aw   = (const float*)d_in[14];
    const float* b_aw   = (const float*)d_in[15];
    const float* w_val  = (const float*)d_in[16];
    const float* b_val  = (const float*)d_in[17];
    const float* w_oc   = (const float*)d_in[18];
    const float* b_oc   = (const float*)d_in[19];
    const float* g_w    = (const float*)d_in[20];
    const float* be_w   = (const float*)d_in[21];
    const float* g_a    = (const float*)d_in[22];
    const float* be_a   = (const float*)d_in[23];
    const float* g1     = (const float*)d_in[24];
    const float* be1    = (const float*)d_in[25];
    const float* g2     = (const float*)d_in[26];
    const float* be2    = (const float*)d_in[27];
    const float* w1     = (const float*)d_in[28];
    const float* b1     = (const float*)d_in[29];
    const float* w2     = (const float*)d_in[30];
    const float* b2     = (const float*)d_in[31];

    float* X  = (float*)d_out;                       // persistent x, 13600x256 fp32
    float* ws = (float*)d_ws;
    float* R1 = ws;                                  // 23,046,144 f (qkv fp32 / value fp32 / H bf16 alias)
    float* R2 = R1 + (size_t)MTOK * 256;             //  3,481,600 f (proj / offsets fp32)
    float* R3 = R2 + (size_t)NTOK * 256;             //  1,740,800 f (attn/deform outs as bf16)
    float* R6 = R3 + (size_t)NTOK * 128;             //  1,740,800 f (raw attn weights fp32)
    float* QBF= R6 + (size_t)NTOK * 128;             //  1,740,800 f (bf16 GEMM A input, 13600x256)
    float* WBF= QBF+ (size_t)NTOK * 128;             //    638,976 f (packed bf16 weights)
    // total ≈ 32.39 M floats = 129.6 MB

    __hip_bfloat16* R3b = (__hip_bfloat16*)R3;
    __hip_bfloat16* Qb  = (__hip_bfloat16*)QBF;
    __hip_bfloat16* Wb  = (__hip_bfloat16*)WBF;
    __hip_bfloat16* Hb  = (__hip_bfloat16*)R1;       // ffn hidden alias (phase 4 only)

    // packed bf16 weight offsets (elements)
    __hip_bfloat16* w_in_w_b  = Wb;                  // 768x256
    __hip_bfloat16* w_out_w_b = Wb +  196608;        // 256x256
    __hip_bfloat16* w_in_a_b  = Wb +  262144;        // 768x256
    __hip_bfloat16* w_out_a_b = Wb +  458752;        // 256x256
    __hip_bfloat16* w_off_b   = Wb +  524288;        // 256x256
    __hip_bfloat16* w_aw_b    = Wb +  589824;        // 128x256
    __hip_bfloat16* w_val_b   = Wb +  622592;        // 256x256
    __hip_bfloat16* w_oc_b    = Wb +  688128;        // 256x256
    __hip_bfloat16* w1_b      = Wb +  753664;        // 1024x256
    __hip_bfloat16* w2_b      = Wb + 1015808;        // 256x1024

    cvt_weights<<<4992, 256, 0, stream>>>(w_in_w, w_out_w, w_in_a, w_out_a, w_off,
                                          w_aw, w_val, w_oc, w1, w2, Wb);

    auto gemm = [&](const __hip_bfloat16* A, const __hip_bfloat16* W, const float* b,
                    float* C, int M, int N, int K, int ldc, int col0) {
        dim3 grid(N / 128, (M + 127) / 128);
        gemm_mfma<false, false, false><<<grid, 256, 0, stream>>>(A, W, b, C, M, N, K, ldc, col0);
    };
    auto gemm_a32 = [&](const float* A, const __hip_bfloat16* W, const float* b,
                        float* C, int M, int N, int K, int ldc, int col0) {
        dim3 grid(N / 128, (M + 127) / 128);
        gemm_mfma<false, false, true><<<grid, 256, 0, stream>>>(A, W, b, C, M, N, K, ldc, col0);
    };

    // ---- Phase 1: group self-attention (S=17) ----
    gather_rows_b<<<NTOK, 256, 0, stream>>>(tgt, qpos, Qb, 0);                    // qk -> bf16
    gemm(Qb, w_in_w_b, b_in_w, R1, NTOK, 512, 256, 768, 0);                       // Q,K
    gemm_a32(tgt, w_in_w_b + 512 * 256, b_in_w + 512, R1, NTOK, 256, 256, 768, 512); // V
    attn17<<<dim3(800, 8), 256, 0, stream>>>(R1, R3b);
    gemm((const __hip_bfloat16*)R3b, w_out_w_b, b_out_w, R2, NTOK, 256, 256, 256, 0);
    res_ln<<<NTOK, 256, 0, stream>>>(tgt, R2, g_w, be_w, X, nullptr, 0);

    // ---- Phase 2: query self-attention (S=100) ----
    gather_rows_b<<<NTOK, 256, 0, stream>>>(X, nullptr, Qb, 1);                   // y -> bf16
    gemm(Qb, w_in_a_b, b_in_a, R1, NTOK, 768, 256, 768, 0);
    attn100<<<dim3(136, 8), 128, 0, stream>>>(R1, R3b);
    gemm((const __hip_bfloat16*)R3b, w_out_a_b, b_out_a, R2, NTOK, 256, 256, 256, 0);
    res_ln<<<NTOK, 256, 0, stream>>>(X, R2, g_a, be_a, X, nullptr, 1);

    // ---- Phase 3: deformable attention ----
    gemm_a32(memory, w_val_b, b_val, R1, MTOK, 256, 256, 256, 0);                 // value (fp32 out)
    gather_rows_b<<<NTOK, 256, 0, stream>>>(X, qpos, Qb, 2);                      // q_d -> bf16
    gemm(Qb, w_off_b, b_off, R2, NTOK, 256, 256, 256, 0);                         // offsets
    gemm(Qb, w_aw_b, b_aw, R6, NTOK, 128, 256, 128, 0);                           // raw attn w
    deform_sample<<<NTOK, 256, 0, stream>>>(R1, R2, R6, ref, R3b);
    gemm((const __hip_bfloat16*)R3b, w_oc_b, b_oc, R2, NTOK, 256, 256, 256, 0);
    res_ln<<<NTOK, 256, 0, stream>>>(X, R2, g1, be1, X, Qb, 2);                   // X + bf16 copy

    // ---- Phase 4: FFN ----
    {
        dim3 grid(DFFd / 128, (NTOK + 127) / 128);
        gemm_mfma<true, true, false><<<grid, 256, 0, stream>>>(Qb, w1_b, b1, Hb,
                                                               NTOK, DFFd, 256, DFFd, 0);
    }
    gemm((const __hip_bfloat16*)Hb, w2_b, b2, R2, NTOK, 256, 1024, 256, 0);
    res_ln<<<NTOK, 256, 0, stream>>>(X, R2, g2, be2, X, nullptr, 0);
}

// Round 7
// 465.232 us; speedup vs baseline: 3.1216x; 1.1268x over previous
//
#include <hip/hip_runtime.h>
#include <hip/hip_bf16.h>
#include <math.h>

#define NQd 100
#define BSd 8
#define NPTd 17
#define DIMd 256
#define NHd 8
#define DHd 32
#define DFFd 1024
#define NTOK (NQd*BSd*NPTd)        // 13600
#define LENIN 11253
#define MTOK (BSd*LENIN)           // 90024

typedef __attribute__((ext_vector_type(8))) short bf16x8;
typedef __attribute__((ext_vector_type(4))) float f32x4;

__device__ inline short f2bs(float f) {
    __hip_bfloat16 h = __float2bfloat16(f);
    return *reinterpret_cast<short*>(&h);
}

// ---------------------------------------------------------------------------
// bf16 MFMA GEMM: C[m][col0+n] = act(A[m][:K] . W[n][:K] + bias[n])
// 128x128 tile, 256 thr (4 waves, 2x2), 4x4 frags of 16x16x32, BK=32.
// ---------------------------------------------------------------------------
template<bool RELU, bool OUT_BF16, bool A_FP32>
__global__ __launch_bounds__(256)
void gemm_mfma(const void* __restrict__ Av, const __hip_bfloat16* __restrict__ W,
               const float* __restrict__ bias, void* __restrict__ Cv,
               int M, int N, int K, int ldc, int col0) {
    __shared__ __hip_bfloat16 As[128][40];
    __shared__ __hip_bfloat16 Ws[128][40];
    const int tid = threadIdx.x;
    const int lane = tid & 63, wave = tid >> 6;
    const int wr = wave >> 1, wc = wave & 1;
    const int m0 = blockIdx.y * 128, n0 = blockIdx.x * 128;
    const int l15 = lane & 15, lg = lane >> 4;

    f32x4 acc[4][4];
#pragma unroll
    for (int i = 0; i < 4; ++i)
#pragma unroll
        for (int j = 0; j < 4; ++j) acc[i][j] = (f32x4){0.f, 0.f, 0.f, 0.f};

    for (int k0 = 0; k0 < K; k0 += 32) {
        __syncthreads();
#pragma unroll
        for (int it = 0; it < 2; ++it) {
            const int L = tid + it * 256;
            const int row = L >> 2, koct = L & 3;
            const int gm = m0 + row;
            bf16x8 av = {0, 0, 0, 0, 0, 0, 0, 0};
            if (A_FP32) {
                if (gm < M) {
                    const float* ap = (const float*)Av + (size_t)gm * K + k0 + koct * 8;
                    float4 f0 = *(const float4*)ap;
                    float4 f1 = *(const float4*)(ap + 4);
                    av = (bf16x8){f2bs(f0.x), f2bs(f0.y), f2bs(f0.z), f2bs(f0.w),
                                  f2bs(f1.x), f2bs(f1.y), f2bs(f1.z), f2bs(f1.w)};
                }
            } else {
                if (gm < M)
                    av = *(const bf16x8*)((const __hip_bfloat16*)Av + (size_t)gm * K + k0 + koct * 8);
            }
            *(bf16x8*)&As[row][koct * 8] = av;
            bf16x8 wv = *(const bf16x8*)(W + (size_t)(n0 + row) * K + k0 + koct * 8);
            *(bf16x8*)&Ws[row][koct * 8] = wv;
        }
        __syncthreads();

        bf16x8 af[4], bfr[4];
#pragma unroll
        for (int f = 0; f < 4; ++f) {
            af[f]  = *(const bf16x8*)&As[wr * 64 + f * 16 + l15][lg * 8];
            bfr[f] = *(const bf16x8*)&Ws[wc * 64 + f * 16 + l15][lg * 8];
        }
#pragma unroll
        for (int fm = 0; fm < 4; ++fm)
#pragma unroll
            for (int fn = 0; fn < 4; ++fn)
                acc[fm][fn] = __builtin_amdgcn_mfma_f32_16x16x32_bf16(af[fm], bfr[fn], acc[fm][fn], 0, 0, 0);
    }

#pragma unroll
    for (int fm = 0; fm < 4; ++fm) {
        const int row = m0 + wr * 64 + fm * 16 + lg * 4;
#pragma unroll
        for (int fn = 0; fn < 4; ++fn) {
            const int coln = n0 + wc * 64 + fn * 16 + l15;
            const float bsv = bias[coln];
#pragma unroll
            for (int r = 0; r < 4; ++r) {
                const int gr = row + r;
                if (gr >= M) continue;
                float v = acc[fm][fn][r] + bsv;
                if (RELU) v = fmaxf(v, 0.f);
                if (OUT_BF16)
                    ((__hip_bfloat16*)Cv)[(size_t)gr * ldc + col0 + coln] = __float2bfloat16(v);
                else
                    ((float*)Cv)[(size_t)gr * ldc + col0 + coln] = v;
            }
        }
    }
}

// ---------------------------------------------------------------------------
// Fused weight conversion fp32 -> bf16 into one packed buffer.
// ---------------------------------------------------------------------------
__global__ void cvt_weights(const float* w0, const float* w1, const float* w2,
                            const float* w3, const float* w4, const float* w5,
                            const float* w6, const float* w7, const float* w8,
                            const float* w9, __hip_bfloat16* dst) {
    int idx = blockIdx.x * 256 + threadIdx.x;
    float v;
    if      (idx <  196608) v = w0[idx];
    else if (idx <  262144) v = w1[idx -  196608];
    else if (idx <  458752) v = w2[idx -  262144];
    else if (idx <  524288) v = w3[idx -  458752];
    else if (idx <  589824) v = w4[idx -  524288];
    else if (idx <  622592) v = w5[idx -  589824];
    else if (idx <  688128) v = w6[idx -  622592];
    else if (idx <  753664) v = w7[idx -  688128];
    else if (idx < 1015808) v = w8[idx -  753664];
    else                    v = w9[idx - 1015808];
    dst[idx] = __float2bfloat16(v);
}

// ---------------------------------------------------------------------------
// Row gather (+optional add) -> contiguous bf16 (t, 256) buffer.
// mode 0: r=t    mode 1: y-order    mode 2: deform q order
// ---------------------------------------------------------------------------
__global__ void gather_rows_b(const float* __restrict__ src, const float* __restrict__ add,
                              __hip_bfloat16* __restrict__ dst, int mode) {
    int t = blockIdx.x, c = threadIdx.x;
    int r;
    if (mode == 0) r = t;
    else if (mode == 1) { int m = t / 100, q = t % 100; r = q * 136 + m; }
    else { int b = t / 1700, jj = t % 1700; int q = jj / 17, p = jj % 17; r = q * 136 + b * 17 + p; }
    float v = src[(size_t)r * 256 + c];
    if (add) v += add[(size_t)r * 256 + c];
    dst[(size_t)t * 256 + c] = __float2bfloat16(v);
}

// ---------------------------------------------------------------------------
// MHA S=17 (group attention). qkv rows: t*768 (Q|K|V). block=(group, head)
// ---------------------------------------------------------------------------
__global__ void attn17(const float* __restrict__ qkv, __hip_bfloat16* __restrict__ out) {
    const int g = blockIdx.x, h = blockIdx.y;
    __shared__ float q[17][32], k[17][32], v[17][32], s[17][18];
    const int tid = threadIdx.x;  // 256
    for (int idx = tid; idx < 17 * 32; idx += 256) {
        int i = idx >> 5, d = idx & 31;
        size_t row = (size_t)(g * 17 + i) * 768 + h * 32 + d;
        q[i][d] = qkv[row];
        k[i][d] = qkv[row + 256];
        v[i][d] = qkv[row + 512];
    }
    __syncthreads();
    for (int idx = tid; idx < 17 * 17; idx += 256) {
        int i = idx / 17, j = idx % 17;
        float acc = 0.f;
#pragma unroll
        for (int d = 0; d < 32; ++d) acc += q[i][d] * k[j][d];
        s[i][j] = acc * 0.17677669529663688f;
    }
    __syncthreads();
    if (tid < 17) {
        float m = -1e30f;
        for (int j = 0; j < 17; ++j) m = fmaxf(m, s[tid][j]);
        float sum = 0.f;
        for (int j = 0; j < 17; ++j) { float e = __expf(s[tid][j] - m); s[tid][j] = e; sum += e; }
        float inv = 1.f / sum;
        for (int j = 0; j < 17; ++j) s[tid][j] *= inv;
    }
    __syncthreads();
    for (int idx = tid; idx < 17 * 32; idx += 256) {
        int i = idx >> 5, d = idx & 31;
        float acc = 0.f;
        for (int j = 0; j < 17; ++j) acc += s[i][j] * v[j][d];
        out[(size_t)(g * 17 + i) * 256 + h * 32 + d] = __float2bfloat16(acc);
    }
}

// ---------------------------------------------------------------------------
// MHA S=100: thread-per-query online softmax. block=(group in 136, head).
// ---------------------------------------------------------------------------
__global__ __launch_bounds__(128)
void attn100(const float* __restrict__ qkv, __hip_bfloat16* __restrict__ out) {
    const int g = blockIdx.x, h = blockIdx.y;
    __shared__ float Ks[100][32], Vs[100][32];
    const int tid = threadIdx.x;  // 128
    for (int idx = tid; idx < 800; idx += 128) {
        int j = idx >> 3, qd = (idx & 7) * 4;
        const float* base = qkv + (size_t)(g * 100 + j) * 768 + h * 32;
        *(float4*)&Ks[j][qd] = *(const float4*)(base + 256 + qd);
        *(float4*)&Vs[j][qd] = *(const float4*)(base + 512 + qd);
    }
    __syncthreads();
    if (tid >= 100) return;
    const float* qp = qkv + (size_t)(g * 100 + tid) * 768 + h * 32;
    float q[32];
#pragma unroll
    for (int d4 = 0; d4 < 32; d4 += 4) {
        float4 v = *(const float4*)(qp + d4);
        q[d4] = v.x; q[d4 + 1] = v.y; q[d4 + 2] = v.z; q[d4 + 3] = v.w;
    }
    float m = -1e30f, l = 0.f, o[32];
#pragma unroll
    for (int d = 0; d < 32; ++d) o[d] = 0.f;
    for (int j = 0; j < 100; ++j) {
        float s = 0.f;
#pragma unroll
        for (int d = 0; d < 32; ++d) s += q[d] * Ks[j][d];
        s *= 0.17677669529663688f;
        float nm = fmaxf(m, s);
        float f = __expf(m - nm), p = __expf(s - nm);
        l = l * f + p;
#pragma unroll
        for (int d = 0; d < 32; ++d) o[d] = o[d] * f + p * Vs[j][d];
        m = nm;
    }
    float inv = 1.f / l;
    __hip_bfloat16* op = out + (size_t)(g * 100 + tid) * 256 + h * 32;
#pragma unroll
    for (int d = 0; d < 32; ++d) op[d] = __float2bfloat16(o[d] * inv);
}

// ---------------------------------------------------------------------------
// Deformable sampling v2: block = 4 tokens, 256 threads.
// Phase A: 128 samples/token -> corner indices + fused weights in LDS.
// Phase B: thread=(token,h,d4) accumulates float4 taps.
// ---------------------------------------------------------------------------
#define TPB 4
__global__ __launch_bounds__(256)
void deform_sample(const float* __restrict__ value, const float* __restrict__ off,
                   const float* __restrict__ aw, const float* __restrict__ ref,
                   __hip_bfloat16* __restrict__ out) {
    const int t0 = blockIdx.x * TPB;
    const int tid = threadIdx.x;
    __shared__ float raw[TPB][128];
    __shared__ float wgt[TPB][128];
    __shared__ int   cidx[TPB][128][4];
    __shared__ float cw[TPB][128][4];

    for (int idx = tid; idx < TPB * 128; idx += 256) {
        int tk = idx >> 7, i = idx & 127;
        raw[tk][i] = aw[(size_t)(t0 + tk) * 128 + i];
    }
    __syncthreads();
    if (tid < TPB * 8) {
        int tk = tid >> 3, h = tid & 7;
        float m = -1e30f;
        for (int i = 0; i < 16; ++i) m = fmaxf(m, raw[tk][h * 16 + i]);
        float sum = 0.f;
        float e[16];
        for (int i = 0; i < 16; ++i) { e[i] = __expf(raw[tk][h * 16 + i] - m); sum += e[i]; }
        float inv = 1.f / sum;
        for (int i = 0; i < 16; ++i) wgt[tk][h * 16 + i] = e[i] * inv;
    }
    __syncthreads();

    const int Hs[4] = {92, 46, 23, 12};
    const int Sts[4] = {0, 8464, 10580, 11109};
    for (int s = tid; s < TPB * 128; s += 256) {
        int tk = s >> 7, sid = s & 127;
        int t = t0 + tk;
        int b = t / 1700, jj = t % 1700;
        int q = jj / 17, p = jj % 17;
        int l = (sid >> 2) & 3;
        int HW = Hs[l];
        float HWf = (float)HW;
        const float* refp = ref + (size_t)((q * 8 + b) * 17 + p) * 8;
        float rx = refp[l * 2], ry = refp[l * 2 + 1];
        float ox = off[(size_t)t * 256 + sid * 2];
        float oy = off[(size_t)t * 256 + sid * 2 + 1];
        float x = (rx + ox / HWf) * HWf - 0.5f;
        float y = (ry + oy / HWf) * HWf - 0.5f;
        float x0f = floorf(x), y0f = floorf(y);
        float wx = x - x0f, wy = y - y0f;
        int xi = (int)x0f, yi = (int)y0f;
        float wg = wgt[tk][sid];
#pragma unroll
        for (int c = 0; c < 4; ++c) {
            int cy = c >> 1, cx = c & 1;
            int yy = yi + cy, xx = xi + cx;
            bool ok = (xx >= 0) && (xx < HW) && (yy >= 0) && (yy < HW);
            int yc = min(max(yy, 0), HW - 1);
            int xc = min(max(xx, 0), HW - 1);
            cidx[tk][sid][c] = Sts[l] + yc * HW + xc;
            float w = (cy ? wy : 1.f - wy) * (cx ? wx : 1.f - wx);
            cw[tk][sid][c] = ok ? wg * w : 0.f;
        }
    }
    __syncthreads();

    const int tk = tid >> 6, lane = tid & 63;
    const int h = lane >> 3, d4 = (lane & 7) * 4;
    const int t = t0 + tk;
    const int b = t / 1700;
    const float* vb = value + (size_t)b * LENIN * 256 + h * 32 + d4;
    float4 acc = make_float4(0.f, 0.f, 0.f, 0.f);
    for (int s16 = 0; s16 < 16; ++s16) {
        int sid = h * 16 + s16;
#pragma unroll
        for (int c = 0; c < 4; ++c) {
            int idx = cidx[tk][sid][c];
            float w = cw[tk][sid][c];
            float4 v = *(const float4*)(vb + (size_t)idx * 256);
            acc.x += w * v.x; acc.y += w * v.y; acc.z += w * v.z; acc.w += w * v.w;
        }
    }
    __hip_bfloat16* op = out + (size_t)t * 256 + h * 32 + d4;
    op[0] = __float2bfloat16(acc.x);
    op[1] = __float2bfloat16(acc.y);
    op[2] = __float2bfloat16(acc.z);
    op[3] = __float2bfloat16(acc.w);
}

// ---------------------------------------------------------------------------
// Residual + LayerNorm over D=256, block per row, proj-row permutation.
// ---------------------------------------------------------------------------
__global__ void res_ln(const float* __restrict__ res, const float* __restrict__ proj,
                       const float* __restrict__ g, const float* __restrict__ be,
                       float* __restrict__ out, __hip_bfloat16* __restrict__ outb, int mode) {
    const int r = blockIdx.x, c = threadIdx.x;
    int t;
    if (mode == 0) t = r;
    else if (mode == 1) { int q = r / 136, m = r % 136; t = m * 100 + q; }
    else { int q = r / 136, rem = r % 136; int b = rem / 17, p = rem % 17; t = b * 1700 + q * 17 + p; }
    float v = res[(size_t)r * 256 + c] + proj[(size_t)t * 256 + c];
    __shared__ float red[256];
    red[c] = v;
    __syncthreads();
    for (int st = 128; st > 0; st >>= 1) {
        if (c < st) red[c] += red[c + st];
        __syncthreads();
    }
    float mean = red[0] * (1.f / 256.f);
    __syncthreads();
    float dv = v - mean;
    red[c] = dv * dv;
    __syncthreads();
    for (int st = 128; st > 0; st >>= 1) {
        if (c < st) red[c] += red[c + st];
        __syncthreads();
    }
    float var = red[0] * (1.f / 256.f);
    float o = dv * rsqrtf(var + 1e-5f) * g[c] + be[c];
    out[(size_t)r * 256 + c] = o;
    if (outb) outb[(size_t)r * 256 + c] = __float2bfloat16(o);
}

// ---------------------------------------------------------------------------
extern "C" void kernel_launch(void* const* d_in, const int* in_sizes, int n_in,
                              void* d_out, int out_size, void* d_ws, size_t ws_size,
                              hipStream_t stream) {
    const float* tgt    = (const float*)d_in[0];
    const float* qpos   = (const float*)d_in[1];
    const float* ref    = (const float*)d_in[2];
    const float* memory = (const float*)d_in[3];
    const float* w_in_w = (const float*)d_in[4];
    const float* b_in_w = (const float*)d_in[5];
    const float* w_out_w= (const float*)d_in[6];
    const float* b_out_w= (const float*)d_in[7];
    const float* w_in_a = (const float*)d_in[8];
    const float* b_in_a = (const float*)d_in[9];
    const float* w_out_a= (const float*)d_in[10];
    const float* b_out_a= (const float*)d_in[11];
    const float* w_off  = (const float*)d_in[12];
    const float* b_off  = (const float*)d_in[13];
    const float* w_aw   = (const float*)d_in[14];
    const float* b_aw   = (const float*)d_in[15];
    const float* w_val  = (const float*)d_in[16];
    const float* b_val  = (const float*)d_in[17];
    const float* w_oc   = (const float*)d_in[18];
    const float* b_oc   = (const float*)d_in[19];
    const float* g_w    = (const float*)d_in[20];
    const float* be_w   = (const float*)d_in[21];
    const float* g_a    = (const float*)d_in[22];
    const float* be_a   = (const float*)d_in[23];
    const float* g1     = (const float*)d_in[24];
    const float* be1    = (const float*)d_in[25];
    const float* g2     = (const float*)d_in[26];
    const float* be2    = (const float*)d_in[27];
    const float* w1     = (const float*)d_in[28];
    const float* b1     = (const float*)d_in[29];
    const float* w2     = (const float*)d_in[30];
    const float* b2     = (const float*)d_in[31];

    float* X  = (float*)d_out;                       // persistent x, 13600x256 fp32
    float* ws = (float*)d_ws;
    float* R1 = ws;                                  // 23,046,144 f
    float* R2 = R1 + (size_t)MTOK * 256;             //  3,481,600 f
    float* R3 = R2 + (size_t)NTOK * 256;             //  1,740,800 f (bf16 attn/deform outs)
    float* R6 = R3 + (size_t)NTOK * 128;             //  1,740,800 f (raw attn weights fp32)
    float* QBF= R6 + (size_t)NTOK * 128;             //  1,740,800 f (bf16 GEMM A input)
    float* WBF= QBF+ (size_t)NTOK * 128;             //    638,976 f (packed bf16 weights)

    __hip_bfloat16* R3b = (__hip_bfloat16*)R3;
    __hip_bfloat16* Qb  = (__hip_bfloat16*)QBF;
    __hip_bfloat16* Wb  = (__hip_bfloat16*)WBF;
    __hip_bfloat16* Hb  = (__hip_bfloat16*)R1;

    __hip_bfloat16* w_in_w_b  = Wb;                  // 768x256
    __hip_bfloat16* w_out_w_b = Wb +  196608;        // 256x256
    __hip_bfloat16* w_in_a_b  = Wb +  262144;        // 768x256
    __hip_bfloat16* w_out_a_b = Wb +  458752;        // 256x256
    __hip_bfloat16* w_off_b   = Wb +  524288;        // 256x256
    __hip_bfloat16* w_aw_b    = Wb +  589824;        // 128x256
    __hip_bfloat16* w_val_b   = Wb +  622592;        // 256x256
    __hip_bfloat16* w_oc_b    = Wb +  688128;        // 256x256
    __hip_bfloat16* w1_b      = Wb +  753664;        // 1024x256
    __hip_bfloat16* w2_b      = Wb + 1015808;        // 256x1024

    cvt_weights<<<4992, 256, 0, stream>>>(w_in_w, w_out_w, w_in_a, w_out_a, w_off,
                                          w_aw, w_val, w_oc, w1, w2, Wb);

    auto gemm = [&](const __hip_bfloat16* A, const __hip_bfloat16* W, const float* b,
                    float* C, int M, int N, int K, int ldc, int col0) {
        dim3 grid(N / 128, (M + 127) / 128);
        gemm_mfma<false, false, false><<<grid, 256, 0, stream>>>(A, W, b, C, M, N, K, ldc, col0);
    };
    auto gemm_a32 = [&](const float* A, const __hip_bfloat16* W, const float* b,
                        float* C, int M, int N, int K, int ldc, int col0) {
        dim3 grid(N / 128, (M + 127) / 128);
        gemm_mfma<false, false, true><<<grid, 256, 0, stream>>>(A, W, b, C, M, N, K, ldc, col0);
    };

    // ---- Phase 1: group self-attention (S=17) ----
    gather_rows_b<<<NTOK, 256, 0, stream>>>(tgt, qpos, Qb, 0);
    gemm(Qb, w_in_w_b, b_in_w, R1, NTOK, 512, 256, 768, 0);
    gemm_a32(tgt, w_in_w_b + 512 * 256, b_in_w + 512, R1, NTOK, 256, 256, 768, 512);
    attn17<<<dim3(800, 8), 256, 0, stream>>>(R1, R3b);
    gemm((const __hip_bfloat16*)R3b, w_out_w_b, b_out_w, R2, NTOK, 256, 256, 256, 0);
    res_ln<<<NTOK, 256, 0, stream>>>(tgt, R2, g_w, be_w, X, nullptr, 0);

    // ---- Phase 2: query self-attention (S=100) ----
    gather_rows_b<<<NTOK, 256, 0, stream>>>(X, nullptr, Qb, 1);
    gemm(Qb, w_in_a_b, b_in_a, R1, NTOK, 768, 256, 768, 0);
    attn100<<<dim3(136, 8), 128, 0, stream>>>(R1, R3b);
    gemm((const __hip_bfloat16*)R3b, w_out_a_b, b_out_a, R2, NTOK, 256, 256, 256, 0);
    res_ln<<<NTOK, 256, 0, stream>>>(X, R2, g_a, be_a, X, nullptr, 1);

    // ---- Phase 3: deformable attention ----
    gemm_a32(memory, w_val_b, b_val, R1, MTOK, 256, 256, 256, 0);
    gather_rows_b<<<NTOK, 256, 0, stream>>>(X, qpos, Qb, 2);
    gemm(Qb, w_off_b, b_off, R2, NTOK, 256, 256, 256, 0);
    gemm(Qb, w_aw_b, b_aw, R6, NTOK, 128, 256, 128, 0);
    deform_sample<<<NTOK / TPB, 256, 0, stream>>>(R1, R2, R6, ref, R3b);
    gemm((const __hip_bfloat16*)R3b, w_oc_b, b_oc, R2, NTOK, 256, 256, 256, 0);
    res_ln<<<NTOK, 256, 0, stream>>>(X, R2, g1, be1, X, Qb, 2);

    // ---- Phase 4: FFN ----
    {
        dim3 grid(DFFd / 128, (NTOK + 127) / 128);
        gemm_mfma<true, true, false><<<grid, 256, 0, stream>>>(Qb, w1_b, b1, Hb,
                                                               NTOK, DFFd, 256, DFFd, 0);
    }
    gemm((const __hip_bfloat16*)Hb, w2_b, b2, R2, NTOK, 256, 1024, 256, 0);
    res_ln<<<NTOK, 256, 0, stream>>>(X, R2, g2, be2, X, nullptr, 0);
}

// Round 8
// 421.314 us; speedup vs baseline: 3.4470x; 1.1042x over previous
//
#include <hip/hip_runtime.h>
#include <hip/hip_bf16.h>
#include <math.h>

#define NQd 100
#define BSd 8
#define NPTd 17
#define DIMd 256
#define NHd 8
#define DHd 32
#define DFFd 1024
#define NTOK (NQd*BSd*NPTd)        // 13600
#define LENIN 11253
#define MTOK (BSd*LENIN)           // 90024

typedef __attribute__((ext_vector_type(8))) short bf16x8;
typedef __attribute__((ext_vector_type(4))) short bf16x4s;
typedef __attribute__((ext_vector_type(4))) float f32x4;

__device__ inline short f2bs(float f) {
    __hip_bfloat16 h = __float2bfloat16(f);
    return *reinterpret_cast<short*>(&h);
}
__device__ inline float bs2f(short s) {
    return __uint_as_float(((unsigned)(unsigned short)s) << 16);
}

// ---------------------------------------------------------------------------
// bf16 MFMA GEMM: C[m][col0+n] = act(A[m][:K] . W[n][:K] + bias[n])
// 128x128 tile, 256 thr (4 waves, 2x2), 4x4 frags of 16x16x32, BK=32.
// Pipelined: issue next-tile global loads BEFORE MFMA of current tile,
// ds_write them AFTER the tail barrier (issue-early / write-late).
// ---------------------------------------------------------------------------
template<bool RELU, bool OUT_BF16, bool A_FP32>
__global__ __launch_bounds__(256)
void gemm_mfma(const void* __restrict__ Av, const __hip_bfloat16* __restrict__ W,
               const float* __restrict__ bias, void* __restrict__ Cv,
               int M, int N, int K, int ldc, int col0) {
    __shared__ __hip_bfloat16 As[128][40];
    __shared__ __hip_bfloat16 Ws[128][40];
    const int tid = threadIdx.x;
    const int lane = tid & 63, wave = tid >> 6;
    const int wr = wave >> 1, wc = wave & 1;
    const int m0 = blockIdx.y * 128, n0 = blockIdx.x * 128;
    const int l15 = lane & 15, lg = lane >> 4;

    const int row_ = tid >> 2, koct = tid & 3;          // it=0 slot
    const int row2 = (tid + 256) >> 2;                   // it=1 slot (koct same)
    const int gm1 = m0 + row_, gm2 = m0 + row2;

    bf16x8 aReg[2], wReg[2];
    auto load_tile = [&](int k0) {
#pragma unroll
        for (int it = 0; it < 2; ++it) {
            const int row = it ? row2 : row_;
            const int gm = it ? gm2 : gm1;
            bf16x8 av = {0, 0, 0, 0, 0, 0, 0, 0};
            if (A_FP32) {
                if (gm < M) {
                    const float* ap = (const float*)Av + (size_t)gm * K + k0 + koct * 8;
                    float4 f0 = *(const float4*)ap;
                    float4 f1 = *(const float4*)(ap + 4);
                    av = (bf16x8){f2bs(f0.x), f2bs(f0.y), f2bs(f0.z), f2bs(f0.w),
                                  f2bs(f1.x), f2bs(f1.y), f2bs(f1.z), f2bs(f1.w)};
                }
            } else {
                if (gm < M)
                    av = *(const bf16x8*)((const __hip_bfloat16*)Av + (size_t)gm * K + k0 + koct * 8);
            }
            aReg[it] = av;
            wReg[it] = *(const bf16x8*)(W + (size_t)(n0 + row) * K + k0 + koct * 8);
        }
    };
    auto write_tile = [&]() {
#pragma unroll
        for (int it = 0; it < 2; ++it) {
            const int row = it ? row2 : row_;
            *(bf16x8*)&As[row][koct * 8] = aReg[it];
            *(bf16x8*)&Ws[row][koct * 8] = wReg[it];
        }
    };

    f32x4 acc[4][4];
#pragma unroll
    for (int i = 0; i < 4; ++i)
#pragma unroll
        for (int j = 0; j < 4; ++j) acc[i][j] = (f32x4){0.f, 0.f, 0.f, 0.f};

    const int NT = K >> 5;
    load_tile(0);
    write_tile();
    for (int t = 0; t < NT; ++t) {
        __syncthreads();                       // tile t visible in LDS
        if (t + 1 < NT) load_tile((t + 1) * 32);   // issue loads; overlap w/ MFMA
        bf16x8 af[4], bfr[4];
#pragma unroll
        for (int f = 0; f < 4; ++f) {
            af[f]  = *(const bf16x8*)&As[wr * 64 + f * 16 + l15][lg * 8];
            bfr[f] = *(const bf16x8*)&Ws[wc * 64 + f * 16 + l15][lg * 8];
        }
#pragma unroll
        for (int fm = 0; fm < 4; ++fm)
#pragma unroll
            for (int fn = 0; fn < 4; ++fn)
                acc[fm][fn] = __builtin_amdgcn_mfma_f32_16x16x32_bf16(af[fm], bfr[fn], acc[fm][fn], 0, 0, 0);
        __syncthreads();                       // everyone done reading tile t
        if (t + 1 < NT) write_tile();          // vmcnt-wait + ds_write next tile
    }

#pragma unroll
    for (int fm = 0; fm < 4; ++fm) {
        const int row = m0 + wr * 64 + fm * 16 + lg * 4;
#pragma unroll
        for (int fn = 0; fn < 4; ++fn) {
            const int coln = n0 + wc * 64 + fn * 16 + l15;
            const float bsv = bias[coln];
#pragma unroll
            for (int r = 0; r < 4; ++r) {
                const int gr = row + r;
                if (gr >= M) continue;
                float v = acc[fm][fn][r] + bsv;
                if (RELU) v = fmaxf(v, 0.f);
                if (OUT_BF16)
                    ((__hip_bfloat16*)Cv)[(size_t)gr * ldc + col0 + coln] = __float2bfloat16(v);
                else
                    ((float*)Cv)[(size_t)gr * ldc + col0 + coln] = v;
            }
        }
    }
}

// ---------------------------------------------------------------------------
// Fused weight conversion fp32 -> bf16 into one packed buffer.
// ---------------------------------------------------------------------------
__global__ void cvt_weights(const float* w0, const float* w1, const float* w2,
                            const float* w3, const float* w4, const float* w5,
                            const float* w6, const float* w7, const float* w8,
                            const float* w9, __hip_bfloat16* dst) {
    int idx = blockIdx.x * 256 + threadIdx.x;
    float v;
    if      (idx <  196608) v = w0[idx];
    else if (idx <  262144) v = w1[idx -  196608];
    else if (idx <  458752) v = w2[idx -  262144];
    else if (idx <  524288) v = w3[idx -  458752];
    else if (idx <  589824) v = w4[idx -  524288];
    else if (idx <  622592) v = w5[idx -  589824];
    else if (idx <  688128) v = w6[idx -  622592];
    else if (idx <  753664) v = w7[idx -  688128];
    else if (idx < 1015808) v = w8[idx -  753664];
    else                    v = w9[idx - 1015808];
    dst[idx] = __float2bfloat16(v);
}

// ---------------------------------------------------------------------------
// Row gather (+optional add) -> contiguous bf16 (t, 256) buffer.
// ---------------------------------------------------------------------------
__global__ void gather_rows_b(const float* __restrict__ src, const float* __restrict__ add,
                              __hip_bfloat16* __restrict__ dst, int mode) {
    int t = blockIdx.x, c = threadIdx.x;
    int r;
    if (mode == 0) r = t;
    else if (mode == 1) { int m = t / 100, q = t % 100; r = q * 136 + m; }
    else { int b = t / 1700, jj = t % 1700; int q = jj / 17, p = jj % 17; r = q * 136 + b * 17 + p; }
    float v = src[(size_t)r * 256 + c];
    if (add) v += add[(size_t)r * 256 + c];
    dst[(size_t)t * 256 + c] = __float2bfloat16(v);
}

// ---------------------------------------------------------------------------
// MHA S=17 (group attention). qkv rows: t*768 (Q|K|V). block=(group, head)
// ---------------------------------------------------------------------------
__global__ void attn17(const float* __restrict__ qkv, __hip_bfloat16* __restrict__ out) {
    const int g = blockIdx.x, h = blockIdx.y;
    __shared__ float q[17][32], k[17][32], v[17][32], s[17][18];
    const int tid = threadIdx.x;  // 256
    for (int idx = tid; idx < 17 * 32; idx += 256) {
        int i = idx >> 5, d = idx & 31;
        size_t row = (size_t)(g * 17 + i) * 768 + h * 32 + d;
        q[i][d] = qkv[row];
        k[i][d] = qkv[row + 256];
        v[i][d] = qkv[row + 512];
    }
    __syncthreads();
    for (int idx = tid; idx < 17 * 17; idx += 256) {
        int i = idx / 17, j = idx % 17;
        float acc = 0.f;
#pragma unroll
        for (int d = 0; d < 32; ++d) acc += q[i][d] * k[j][d];
        s[i][j] = acc * 0.17677669529663688f;
    }
    __syncthreads();
    if (tid < 17) {
        float m = -1e30f;
        for (int j = 0; j < 17; ++j) m = fmaxf(m, s[tid][j]);
        float sum = 0.f;
        for (int j = 0; j < 17; ++j) { float e = __expf(s[tid][j] - m); s[tid][j] = e; sum += e; }
        float inv = 1.f / sum;
        for (int j = 0; j < 17; ++j) s[tid][j] *= inv;
    }
    __syncthreads();
    for (int idx = tid; idx < 17 * 32; idx += 256) {
        int i = idx >> 5, d = idx & 31;
        float acc = 0.f;
        for (int j = 0; j < 17; ++j) acc += s[i][j] * v[j][d];
        out[(size_t)(g * 17 + i) * 256 + h * 32 + d] = __float2bfloat16(acc);
    }
}

// ---------------------------------------------------------------------------
// MHA S=100: thread-per-query online softmax. block=(group in 136, head).
// ---------------------------------------------------------------------------
__global__ __launch_bounds__(128)
void attn100(const float* __restrict__ qkv, __hip_bfloat16* __restrict__ out) {
    const int g = blockIdx.x, h = blockIdx.y;
    __shared__ float Ks[100][32], Vs[100][32];
    const int tid = threadIdx.x;  // 128
    for (int idx = tid; idx < 800; idx += 128) {
        int j = idx >> 3, qd = (idx & 7) * 4;
        const float* base = qkv + (size_t)(g * 100 + j) * 768 + h * 32;
        *(float4*)&Ks[j][qd] = *(const float4*)(base + 256 + qd);
        *(float4*)&Vs[j][qd] = *(const float4*)(base + 512 + qd);
    }
    __syncthreads();
    if (tid >= 100) return;
    const float* qp = qkv + (size_t)(g * 100 + tid) * 768 + h * 32;
    float q[32];
#pragma unroll
    for (int d4 = 0; d4 < 32; d4 += 4) {
        float4 v = *(const float4*)(qp + d4);
        q[d4] = v.x; q[d4 + 1] = v.y; q[d4 + 2] = v.z; q[d4 + 3] = v.w;
    }
    float m = -1e30f, l = 0.f, o[32];
#pragma unroll
    for (int d = 0; d < 32; ++d) o[d] = 0.f;
    for (int j = 0; j < 100; ++j) {
        float s = 0.f;
#pragma unroll
        for (int d = 0; d < 32; ++d) s += q[d] * Ks[j][d];
        s *= 0.17677669529663688f;
        float nm = fmaxf(m, s);
        float f = __expf(m - nm), p = __expf(s - nm);
        l = l * f + p;
#pragma unroll
        for (int d = 0; d < 32; ++d) o[d] = o[d] * f + p * Vs[j][d];
        m = nm;
    }
    float inv = 1.f / l;
    __hip_bfloat16* op = out + (size_t)(g * 100 + tid) * 256 + h * 32;
#pragma unroll
    for (int d = 0; d < 32; ++d) op[d] = __float2bfloat16(o[d] * inv);
}

// ---------------------------------------------------------------------------
// Deformable sampling v3: bf16 value input. block = 4 tokens, 256 threads.
// ---------------------------------------------------------------------------
#define TPB 4
__global__ __launch_bounds__(256)
void deform_sample(const __hip_bfloat16* __restrict__ value, const float* __restrict__ off,
                   const float* __restrict__ aw, const float* __restrict__ ref,
                   __hip_bfloat16* __restrict__ out) {
    const int t0 = blockIdx.x * TPB;
    const int tid = threadIdx.x;
    __shared__ float raw[TPB][128];
    __shared__ float wgt[TPB][128];
    __shared__ int   cidx[TPB][128][4];
    __shared__ float cw[TPB][128][4];

    for (int idx = tid; idx < TPB * 128; idx += 256) {
        int tk = idx >> 7, i = idx & 127;
        raw[tk][i] = aw[(size_t)(t0 + tk) * 128 + i];
    }
    __syncthreads();
    if (tid < TPB * 8) {
        int tk = tid >> 3, h = tid & 7;
        float m = -1e30f;
        for (int i = 0; i < 16; ++i) m = fmaxf(m, raw[tk][h * 16 + i]);
        float sum = 0.f;
        float e[16];
        for (int i = 0; i < 16; ++i) { e[i] = __expf(raw[tk][h * 16 + i] - m); sum += e[i]; }
        float inv = 1.f / sum;
        for (int i = 0; i < 16; ++i) wgt[tk][h * 16 + i] = e[i] * inv;
    }
    __syncthreads();

    const int Hs[4] = {92, 46, 23, 12};
    const int Sts[4] = {0, 8464, 10580, 11109};
    for (int s = tid; s < TPB * 128; s += 256) {
        int tk = s >> 7, sid = s & 127;
        int t = t0 + tk;
        int b = t / 1700, jj = t % 1700;
        int q = jj / 17, p = jj % 17;
        int l = (sid >> 2) & 3;
        int HW = Hs[l];
        float HWf = (float)HW;
        const float* refp = ref + (size_t)((q * 8 + b) * 17 + p) * 8;
        float rx = refp[l * 2], ry = refp[l * 2 + 1];
        float ox = off[(size_t)t * 256 + sid * 2];
        float oy = off[(size_t)t * 256 + sid * 2 + 1];
        float x = (rx + ox / HWf) * HWf - 0.5f;
        float y = (ry + oy / HWf) * HWf - 0.5f;
        float x0f = floorf(x), y0f = floorf(y);
        float wx = x - x0f, wy = y - y0f;
        int xi = (int)x0f, yi = (int)y0f;
        float wg = wgt[tk][sid];
#pragma unroll
        for (int c = 0; c < 4; ++c) {
            int cy = c >> 1, cx = c & 1;
            int yy = yi + cy, xx = xi + cx;
            bool ok = (xx >= 0) && (xx < HW) && (yy >= 0) && (yy < HW);
            int yc = min(max(yy, 0), HW - 1);
            int xc = min(max(xx, 0), HW - 1);
            cidx[tk][sid][c] = Sts[l] + yc * HW + xc;
            float w = (cy ? wy : 1.f - wy) * (cx ? wx : 1.f - wx);
            cw[tk][sid][c] = ok ? wg * w : 0.f;
        }
    }
    __syncthreads();

    const int tk = tid >> 6, lane = tid & 63;
    const int h = lane >> 3, d4 = (lane & 7) * 4;
    const int t = t0 + tk;
    const int b = t / 1700;
    const __hip_bfloat16* vb = value + (size_t)b * LENIN * 256 + h * 32 + d4;
    float4 acc = make_float4(0.f, 0.f, 0.f, 0.f);
    for (int s16 = 0; s16 < 16; ++s16) {
        int sid = h * 16 + s16;
#pragma unroll
        for (int c = 0; c < 4; ++c) {
            int idx = cidx[tk][sid][c];
            float w = cw[tk][sid][c];
            bf16x4s v = *(const bf16x4s*)(vb + (size_t)idx * 256);
            acc.x += w * bs2f(v.x); acc.y += w * bs2f(v.y);
            acc.z += w * bs2f(v.z); acc.w += w * bs2f(v.w);
        }
    }
    __hip_bfloat16* op = out + (size_t)t * 256 + h * 32 + d4;
    op[0] = __float2bfloat16(acc.x);
    op[1] = __float2bfloat16(acc.y);
    op[2] = __float2bfloat16(acc.z);
    op[3] = __float2bfloat16(acc.w);
}

// ---------------------------------------------------------------------------
// Residual + LayerNorm over D=256, block per row, proj-row permutation.
// ---------------------------------------------------------------------------
__global__ void res_ln(const float* __restrict__ res, const float* __restrict__ proj,
                       const float* __restrict__ g, const float* __restrict__ be,
                       float* __restrict__ out, __hip_bfloat16* __restrict__ outb, int mode) {
    const int r = blockIdx.x, c = threadIdx.x;
    int t;
    if (mode == 0) t = r;
    else if (mode == 1) { int q = r / 136, m = r % 136; t = m * 100 + q; }
    else { int q = r / 136, rem = r % 136; int b = rem / 17, p = rem % 17; t = b * 1700 + q * 17 + p; }
    float v = res[(size_t)r * 256 + c] + proj[(size_t)t * 256 + c];
    __shared__ float red[256];
    red[c] = v;
    __syncthreads();
    for (int st = 128; st > 0; st >>= 1) {
        if (c < st) red[c] += red[c + st];
        __syncthreads();
    }
    float mean = red[0] * (1.f / 256.f);
    __syncthreads();
    float dv = v - mean;
    red[c] = dv * dv;
    __syncthreads();
    for (int st = 128; st > 0; st >>= 1) {
        if (c < st) red[c] += red[c + st];
        __syncthreads();
    }
    float var = red[0] * (1.f / 256.f);
    float o = dv * rsqrtf(var + 1e-5f) * g[c] + be[c];
    out[(size_t)r * 256 + c] = o;
    if (outb) outb[(size_t)r * 256 + c] = __float2bfloat16(o);
}

// ---------------------------------------------------------------------------
extern "C" void kernel_launch(void* const* d_in, const int* in_sizes, int n_in,
                              void* d_out, int out_size, void* d_ws, size_t ws_size,
                              hipStream_t stream) {
    const float* tgt    = (const float*)d_in[0];
    const float* qpos   = (const float*)d_in[1];
    const float* ref    = (const float*)d_in[2];
    const float* memory = (const float*)d_in[3];
    const float* w_in_w = (const float*)d_in[4];
    const float* b_in_w = (const float*)d_in[5];
    const float* w_out_w= (const float*)d_in[6];
    const float* b_out_w= (const float*)d_in[7];
    const float* w_in_a = (const float*)d_in[8];
    const float* b_in_a = (const float*)d_in[9];
    const float* w_out_a= (const float*)d_in[10];
    const float* b_out_a= (const float*)d_in[11];
    const float* w_off  = (const float*)d_in[12];
    const float* b_off  = (const float*)d_in[13];
    const float* w_aw   = (const float*)d_in[14];
    const float* b_aw   = (const float*)d_in[15];
    const float* w_val  = (const float*)d_in[16];
    const float* b_val  = (const float*)d_in[17];
    const float* w_oc   = (const float*)d_in[18];
    const float* b_oc   = (const float*)d_in[19];
    const float* g_w    = (const float*)d_in[20];
    const float* be_w   = (const float*)d_in[21];
    const float* g_a    = (const float*)d_in[22];
    const float* be_a   = (const float*)d_in[23];
    const float* g1     = (const float*)d_in[24];
    const float* be1    = (const float*)d_in[25];
    const float* g2     = (const float*)d_in[26];
    const float* be2    = (const float*)d_in[27];
    const float* w1     = (const float*)d_in[28];
    const float* b1     = (const float*)d_in[29];
    const float* w2     = (const float*)d_in[30];
    const float* b2     = (const float*)d_in[31];

    float* X  = (float*)d_out;                       // persistent x, 13600x256 fp32
    float* ws = (float*)d_ws;
    float* R1 = ws;                                  // 23,046,144 f (qkv fp32 / value bf16 / H bf16)
    float* R2 = R1 + (size_t)MTOK * 256;             //  3,481,600 f
    float* R3 = R2 + (size_t)NTOK * 256;             //  1,740,800 f (bf16 attn/deform outs)
    float* R6 = R3 + (size_t)NTOK * 128;             //  1,740,800 f (raw attn weights fp32)
    float* QBF= R6 + (size_t)NTOK * 128;             //  1,740,800 f (bf16 GEMM A input)
    float* WBF= QBF+ (size_t)NTOK * 128;             //    638,976 f (packed bf16 weights)

    __hip_bfloat16* R3b = (__hip_bfloat16*)R3;
    __hip_bfloat16* Qb  = (__hip_bfloat16*)QBF;
    __hip_bfloat16* Wb  = (__hip_bfloat16*)WBF;
    __hip_bfloat16* Hb  = (__hip_bfloat16*)R1;       // ffn hidden alias (phase 4)
    __hip_bfloat16* Vb  = (__hip_bfloat16*)R1;       // bf16 value alias (phase 3)

    __hip_bfloat16* w_in_w_b  = Wb;                  // 768x256
    __hip_bfloat16* w_out_w_b = Wb +  196608;        // 256x256
    __hip_bfloat16* w_in_a_b  = Wb +  262144;        // 768x256
    __hip_bfloat16* w_out_a_b = Wb +  458752;        // 256x256
    __hip_bfloat16* w_off_b   = Wb +  524288;        // 256x256
    __hip_bfloat16* w_aw_b    = Wb +  589824;        // 128x256
    __hip_bfloat16* w_val_b   = Wb +  622592;        // 256x256
    __hip_bfloat16* w_oc_b    = Wb +  688128;        // 256x256
    __hip_bfloat16* w1_b      = Wb +  753664;        // 1024x256
    __hip_bfloat16* w2_b      = Wb + 1015808;        // 256x1024

    cvt_weights<<<4992, 256, 0, stream>>>(w_in_w, w_out_w, w_in_a, w_out_a, w_off,
                                          w_aw, w_val, w_oc, w1, w2, Wb);

    auto gemm = [&](const __hip_bfloat16* A, const __hip_bfloat16* W, const float* b,
                    float* C, int M, int N, int K, int ldc, int col0) {
        dim3 grid(N / 128, (M + 127) / 128);
        gemm_mfma<false, false, false><<<grid, 256, 0, stream>>>(A, W, b, C, M, N, K, ldc, col0);
    };
    auto gemm_a32 = [&](const float* A, const __hip_bfloat16* W, const float* b,
                        float* C, int M, int N, int K, int ldc, int col0) {
        dim3 grid(N / 128, (M + 127) / 128);
        gemm_mfma<false, false, true><<<grid, 256, 0, stream>>>(A, W, b, C, M, N, K, ldc, col0);
    };

    // ---- Phase 1: group self-attention (S=17) ----
    gather_rows_b<<<NTOK, 256, 0, stream>>>(tgt, qpos, Qb, 0);
    gemm(Qb, w_in_w_b, b_in_w, R1, NTOK, 512, 256, 768, 0);
    gemm_a32(tgt, w_in_w_b + 512 * 256, b_in_w + 512, R1, NTOK, 256, 256, 768, 512);
    attn17<<<dim3(800, 8), 256, 0, stream>>>(R1, R3b);
    gemm((const __hip_bfloat16*)R3b, w_out_w_b, b_out_w, R2, NTOK, 256, 256, 256, 0);
    res_ln<<<NTOK, 256, 0, stream>>>(tgt, R2, g_w, be_w, X, nullptr, 0);

    // ---- Phase 2: query self-attention (S=100) ----
    gather_rows_b<<<NTOK, 256, 0, stream>>>(X, nullptr, Qb, 1);
    gemm(Qb, w_in_a_b, b_in_a, R1, NTOK, 768, 256, 768, 0);
    attn100<<<dim3(136, 8), 128, 0, stream>>>(R1, R3b);
    gemm((const __hip_bfloat16*)R3b, w_out_a_b, b_out_a, R2, NTOK, 256, 256, 256, 0);
    res_ln<<<NTOK, 256, 0, stream>>>(X, R2, g_a, be_a, X, nullptr, 1);

    // ---- Phase 3: deformable attention ----
    {   // value projection -> bf16 output
        dim3 grid(256 / 128, (MTOK + 127) / 128);
        gemm_mfma<false, true, true><<<grid, 256, 0, stream>>>(memory, w_val_b, b_val, Vb,
                                                               MTOK, 256, 256, 256, 0);
    }
    gather_rows_b<<<NTOK, 256, 0, stream>>>(X, qpos, Qb, 2);
    gemm(Qb, w_off_b, b_off, R2, NTOK, 256, 256, 256, 0);
    gemm(Qb, w_aw_b, b_aw, R6, NTOK, 128, 256, 128, 0);
    deform_sample<<<NTOK / TPB, 256, 0, stream>>>(Vb, R2, R6, ref, R3b);
    gemm((const __hip_bfloat16*)R3b, w_oc_b, b_oc, R2, NTOK, 256, 256, 256, 0);
    res_ln<<<NTOK, 256, 0, stream>>>(X, R2, g1, be1, X, Qb, 2);

    // ---- Phase 4: FFN ----
    {
        dim3 grid(DFFd / 128, (NTOK + 127) / 128);
        gemm_mfma<true, true, false><<<grid, 256, 0, stream>>>(Qb, w1_b, b1, Hb,
                                                               NTOK, DFFd, 256, DFFd, 0);
    }
    gemm((const __hip_bfloat16*)Hb, w2_b, b2, R2, NTOK, 256, 1024, 256, 0);
    res_ln<<<NTOK, 256, 0, stream>>>(X, R2, g2, be2, X, nullptr, 0);
}

// Round 9
// 391.871 us; speedup vs baseline: 3.7060x; 1.0751x over previous
//
#include <hip/hip_runtime.h>
#include <hip/hip_bf16.h>
#include <math.h>

#define NQd 100
#define BSd 8
#define NPTd 17
#define DIMd 256
#define NHd 8
#define DHd 32
#define DFFd 1024
#define NTOK (NQd*BSd*NPTd)        // 13600
#define LENIN 11253
#define MTOK (BSd*LENIN)           // 90024

typedef __attribute__((ext_vector_type(8))) short bf16x8;
typedef __attribute__((ext_vector_type(4))) short bf16x4s;
typedef __attribute__((ext_vector_type(4))) float f32x4;

__device__ inline short f2bs(float f) {
    __hip_bfloat16 h = __float2bfloat16(f);
    return *reinterpret_cast<short*>(&h);
}
__device__ inline float bs2f(short s) {
    return __uint_as_float(((unsigned)(unsigned short)s) << 16);
}

// ---------------------------------------------------------------------------
// bf16 MFMA GEMM: C[m][col0+n] = act(A[m][:K] . W[n][:K] + bias[n])
// 128x128 tile, 256 thr (4 waves 2x2), 4x4 frags of 16x16x32, BK=32.
// LDS layout [koct][row][8] with row-dim 129 (koct stride 516 words, mod32=4):
//   - staging writes (koct 0..3, same row) start banks {0,4,8,12}: conflict-free
//   - frag reads: 16 contiguous rows x 16B = all 32 banks 2-way (free)
// Double-buffered, ONE barrier per K-tile; global loads issued before MFMA.
// ---------------------------------------------------------------------------
template<bool RELU, bool OUT_BF16, bool A_FP32>
__global__ __launch_bounds__(256)
void gemm_mfma(const void* __restrict__ Av, const __hip_bfloat16* __restrict__ W,
               const float* __restrict__ bias, void* __restrict__ Cv,
               int M, int N, int K, int ldc, int col0) {
    __shared__ __hip_bfloat16 LA[2][4][129][8];
    __shared__ __hip_bfloat16 LW[2][4][129][8];
    const int tid = threadIdx.x;
    const int lane = tid & 63, wave = tid >> 6;
    const int wr = wave >> 1, wc = wave & 1;
    const int m0 = blockIdx.y * 128, n0 = blockIdx.x * 128;
    const int l15 = lane & 15, lg = lane >> 4;

    const int srow = tid >> 2;          // 0..63 (it adds 64)
    const int koct = tid & 3;           // k-octet 0..3
    bf16x8 aReg[2], wReg[2];

    auto load_tile = [&](int k0) {
#pragma unroll
        for (int it = 0; it < 2; ++it) {
            const int row = srow + it * 64;
            const int gm = m0 + row;
            bf16x8 av = {0, 0, 0, 0, 0, 0, 0, 0};
            if (A_FP32) {
                if (gm < M) {
                    const float* ap = (const float*)Av + (size_t)gm * K + k0 + koct * 8;
                    float4 f0 = *(const float4*)ap;
                    float4 f1 = *(const float4*)(ap + 4);
                    av = (bf16x8){f2bs(f0.x), f2bs(f0.y), f2bs(f0.z), f2bs(f0.w),
                                  f2bs(f1.x), f2bs(f1.y), f2bs(f1.z), f2bs(f1.w)};
                }
            } else {
                if (gm < M)
                    av = *(const bf16x8*)((const __hip_bfloat16*)Av + (size_t)gm * K + k0 + koct * 8);
            }
            aReg[it] = av;
            wReg[it] = *(const bf16x8*)(W + (size_t)(n0 + row) * K + k0 + koct * 8);
        }
    };
    auto write_tile = [&](int buf) {
#pragma unroll
        for (int it = 0; it < 2; ++it) {
            const int row = srow + it * 64;
            *(bf16x8*)&LA[buf][koct][row][0] = aReg[it];
            *(bf16x8*)&LW[buf][koct][row][0] = wReg[it];
        }
    };

    f32x4 acc[4][4];
#pragma unroll
    for (int i = 0; i < 4; ++i)
#pragma unroll
        for (int j = 0; j < 4; ++j) acc[i][j] = (f32x4){0.f, 0.f, 0.f, 0.f};

    const int NT = K >> 5;
    load_tile(0);
    write_tile(0);
    __syncthreads();
    for (int t = 0; t < NT; ++t) {
        const int cur = t & 1;
        if (t + 1 < NT) load_tile((t + 1) * 32);   // issue next-tile loads early
        bf16x8 af[4], bfr[4];
#pragma unroll
        for (int f = 0; f < 4; ++f) {
            af[f]  = *(const bf16x8*)&LA[cur][lg][wr * 64 + f * 16 + l15][0];
            bfr[f] = *(const bf16x8*)&LW[cur][lg][wc * 64 + f * 16 + l15][0];
        }
#pragma unroll
        for (int fm = 0; fm < 4; ++fm)
#pragma unroll
            for (int fn = 0; fn < 4; ++fn)
                acc[fm][fn] = __builtin_amdgcn_mfma_f32_16x16x32_bf16(af[fm], bfr[fn], acc[fm][fn], 0, 0, 0);
        if (t + 1 < NT) write_tile(cur ^ 1);       // other buffer: nobody reads it
        __syncthreads();                            // single barrier per tile
    }

#pragma unroll
    for (int fm = 0; fm < 4; ++fm) {
        const int row = m0 + wr * 64 + fm * 16 + lg * 4;
#pragma unroll
        for (int fn = 0; fn < 4; ++fn) {
            const int coln = n0 + wc * 64 + fn * 16 + l15;
            const float bsv = bias[coln];
#pragma unroll
            for (int r = 0; r < 4; ++r) {
                const int gr = row + r;
                if (gr >= M) continue;
                float v = acc[fm][fn][r] + bsv;
                if (RELU) v = fmaxf(v, 0.f);
                if (OUT_BF16)
                    ((__hip_bfloat16*)Cv)[(size_t)gr * ldc + col0 + coln] = __float2bfloat16(v);
                else
                    ((float*)Cv)[(size_t)gr * ldc + col0 + coln] = v;
            }
        }
    }
}

// ---------------------------------------------------------------------------
// Fused weight conversion fp32 -> bf16 into one packed buffer.
// ---------------------------------------------------------------------------
__global__ void cvt_weights(const float* w0, const float* w1, const float* w2,
                            const float* w3, const float* w4, const float* w5,
                            const float* w6, const float* w7, const float* w8,
                            const float* w9, __hip_bfloat16* dst) {
    int idx = blockIdx.x * 256 + threadIdx.x;
    float v;
    if      (idx <  196608) v = w0[idx];
    else if (idx <  262144) v = w1[idx -  196608];
    else if (idx <  458752) v = w2[idx -  262144];
    else if (idx <  524288) v = w3[idx -  458752];
    else if (idx <  589824) v = w4[idx -  524288];
    else if (idx <  622592) v = w5[idx -  589824];
    else if (idx <  688128) v = w6[idx -  622592];
    else if (idx <  753664) v = w7[idx -  688128];
    else if (idx < 1015808) v = w8[idx -  753664];
    else                    v = w9[idx - 1015808];
    dst[idx] = __float2bfloat16(v);
}

// ---------------------------------------------------------------------------
// Row gather (+optional add) -> contiguous bf16 (t, 256) buffer.
// ---------------------------------------------------------------------------
__global__ void gather_rows_b(const float* __restrict__ src, const float* __restrict__ add,
                              __hip_bfloat16* __restrict__ dst, int mode) {
    int t = blockIdx.x, c = threadIdx.x;
    int r;
    if (mode == 0) r = t;
    else if (mode == 1) { int m = t / 100, q = t % 100; r = q * 136 + m; }
    else { int b = t / 1700, jj = t % 1700; int q = jj / 17, p = jj % 17; r = q * 136 + b * 17 + p; }
    float v = src[(size_t)r * 256 + c];
    if (add) v += add[(size_t)r * 256 + c];
    dst[(size_t)t * 256 + c] = __float2bfloat16(v);
}

// ---------------------------------------------------------------------------
// MHA S=17 (group attention). qkv rows: t*768 (Q|K|V). block=(group, head)
// ---------------------------------------------------------------------------
__global__ void attn17(const float* __restrict__ qkv, __hip_bfloat16* __restrict__ out) {
    const int g = blockIdx.x, h = blockIdx.y;
    __shared__ float q[17][32], k[17][32], v[17][32], s[17][18];
    const int tid = threadIdx.x;  // 256
    for (int idx = tid; idx < 17 * 32; idx += 256) {
        int i = idx >> 5, d = idx & 31;
        size_t row = (size_t)(g * 17 + i) * 768 + h * 32 + d;
        q[i][d] = qkv[row];
        k[i][d] = qkv[row + 256];
        v[i][d] = qkv[row + 512];
    }
    __syncthreads();
    for (int idx = tid; idx < 17 * 17; idx += 256) {
        int i = idx / 17, j = idx % 17;
        float acc = 0.f;
#pragma unroll
        for (int d = 0; d < 32; ++d) acc += q[i][d] * k[j][d];
        s[i][j] = acc * 0.17677669529663688f;
    }
    __syncthreads();
    if (tid < 17) {
        float m = -1e30f;
        for (int j = 0; j < 17; ++j) m = fmaxf(m, s[tid][j]);
        float sum = 0.f;
        for (int j = 0; j < 17; ++j) { float e = __expf(s[tid][j] - m); s[tid][j] = e; sum += e; }
        float inv = 1.f / sum;
        for (int j = 0; j < 17; ++j) s[tid][j] *= inv;
    }
    __syncthreads();
    for (int idx = tid; idx < 17 * 32; idx += 256) {
        int i = idx >> 5, d = idx & 31;
        float acc = 0.f;
        for (int j = 0; j < 17; ++j) acc += s[i][j] * v[j][d];
        out[(size_t)(g * 17 + i) * 256 + h * 32 + d] = __float2bfloat16(acc);
    }
}

// ---------------------------------------------------------------------------
// MHA S=100: thread-per-query online softmax. block=(group in 136, head).
// ---------------------------------------------------------------------------
__global__ __launch_bounds__(128)
void attn100(const float* __restrict__ qkv, __hip_bfloat16* __restrict__ out) {
    const int g = blockIdx.x, h = blockIdx.y;
    __shared__ float Ks[100][32], Vs[100][32];
    const int tid = threadIdx.x;  // 128
    for (int idx = tid; idx < 800; idx += 128) {
        int j = idx >> 3, qd = (idx & 7) * 4;
        const float* base = qkv + (size_t)(g * 100 + j) * 768 + h * 32;
        *(float4*)&Ks[j][qd] = *(const float4*)(base + 256 + qd);
        *(float4*)&Vs[j][qd] = *(const float4*)(base + 512 + qd);
    }
    __syncthreads();
    if (tid >= 100) return;
    const float* qp = qkv + (size_t)(g * 100 + tid) * 768 + h * 32;
    float q[32];
#pragma unroll
    for (int d4 = 0; d4 < 32; d4 += 4) {
        float4 v = *(const float4*)(qp + d4);
        q[d4] = v.x; q[d4 + 1] = v.y; q[d4 + 2] = v.z; q[d4 + 3] = v.w;
    }
    float m = -1e30f, l = 0.f, o[32];
#pragma unroll
    for (int d = 0; d < 32; ++d) o[d] = 0.f;
    for (int j = 0; j < 100; ++j) {
        float s = 0.f;
#pragma unroll
        for (int d = 0; d < 32; ++d) s += q[d] * Ks[j][d];
        s *= 0.17677669529663688f;
        float nm = fmaxf(m, s);
        float f = __expf(m - nm), p = __expf(s - nm);
        l = l * f + p;
#pragma unroll
        for (int d = 0; d < 32; ++d) o[d] = o[d] * f + p * Vs[j][d];
        m = nm;
    }
    float inv = 1.f / l;
    __hip_bfloat16* op = out + (size_t)(g * 100 + tid) * 256 + h * 32;
#pragma unroll
    for (int d = 0; d < 32; ++d) op[d] = __float2bfloat16(o[d] * inv);
}

// ---------------------------------------------------------------------------
// Deformable sampling v3: bf16 value input. block = 4 tokens, 256 threads.
// ---------------------------------------------------------------------------
#define TPB 4
__global__ __launch_bounds__(256)
void deform_sample(const __hip_bfloat16* __restrict__ value, const float* __restrict__ off,
                   const float* __restrict__ aw, const float* __restrict__ ref,
                   __hip_bfloat16* __restrict__ out) {
    const int t0 = blockIdx.x * TPB;
    const int tid = threadIdx.x;
    __shared__ float raw[TPB][128];
    __shared__ float wgt[TPB][128];
    __shared__ int   cidx[TPB][128][4];
    __shared__ float cw[TPB][128][4];

    for (int idx = tid; idx < TPB * 128; idx += 256) {
        int tk = idx >> 7, i = idx & 127;
        raw[tk][i] = aw[(size_t)(t0 + tk) * 128 + i];
    }
    __syncthreads();
    if (tid < TPB * 8) {
        int tk = tid >> 3, h = tid & 7;
        float m = -1e30f;
        for (int i = 0; i < 16; ++i) m = fmaxf(m, raw[tk][h * 16 + i]);
        float sum = 0.f;
        float e[16];
        for (int i = 0; i < 16; ++i) { e[i] = __expf(raw[tk][h * 16 + i] - m); sum += e[i]; }
        float inv = 1.f / sum;
        for (int i = 0; i < 16; ++i) wgt[tk][h * 16 + i] = e[i] * inv;
    }
    __syncthreads();

    const int Hs[4] = {92, 46, 23, 12};
    const int Sts[4] = {0, 8464, 10580, 11109};
    for (int s = tid; s < TPB * 128; s += 256) {
        int tk = s >> 7, sid = s & 127;
        int t = t0 + tk;
        int b = t / 1700, jj = t % 1700;
        int q = jj / 17, p = jj % 17;
        int l = (sid >> 2) & 3;
        int HW = Hs[l];
        float HWf = (float)HW;
        const float* refp = ref + (size_t)((q * 8 + b) * 17 + p) * 8;
        float rx = refp[l * 2], ry = refp[l * 2 + 1];
        float ox = off[(size_t)t * 256 + sid * 2];
        float oy = off[(size_t)t * 256 + sid * 2 + 1];
        float x = (rx + ox / HWf) * HWf - 0.5f;
        float y = (ry + oy / HWf) * HWf - 0.5f;
        float x0f = floorf(x), y0f = floorf(y);
        float wx = x - x0f, wy = y - y0f;
        int xi = (int)x0f, yi = (int)y0f;
        float wg = wgt[tk][sid];
#pragma unroll
        for (int c = 0; c < 4; ++c) {
            int cy = c >> 1, cx = c & 1;
            int yy = yi + cy, xx = xi + cx;
            bool ok = (xx >= 0) && (xx < HW) && (yy >= 0) && (yy < HW);
            int yc = min(max(yy, 0), HW - 1);
            int xc = min(max(xx, 0), HW - 1);
            cidx[tk][sid][c] = Sts[l] + yc * HW + xc;
            float w = (cy ? wy : 1.f - wy) * (cx ? wx : 1.f - wx);
            cw[tk][sid][c] = ok ? wg * w : 0.f;
        }
    }
    __syncthreads();

    const int tk = tid >> 6, lane = tid & 63;
    const int h = lane >> 3, d4 = (lane & 7) * 4;
    const int t = t0 + tk;
    const int b = t / 1700;
    const __hip_bfloat16* vb = value + (size_t)b * LENIN * 256 + h * 32 + d4;
    float4 acc = make_float4(0.f, 0.f, 0.f, 0.f);
    for (int s16 = 0; s16 < 16; ++s16) {
        int sid = h * 16 + s16;
#pragma unroll
        for (int c = 0; c < 4; ++c) {
            int idx = cidx[tk][sid][c];
            float w = cw[tk][sid][c];
            bf16x4s v = *(const bf16x4s*)(vb + (size_t)idx * 256);
            acc.x += w * bs2f(v.x); acc.y += w * bs2f(v.y);
            acc.z += w * bs2f(v.z); acc.w += w * bs2f(v.w);
        }
    }
    __hip_bfloat16* op = out + (size_t)t * 256 + h * 32 + d4;
    op[0] = __float2bfloat16(acc.x);
    op[1] = __float2bfloat16(acc.y);
    op[2] = __float2bfloat16(acc.z);
    op[3] = __float2bfloat16(acc.w);
}

// ---------------------------------------------------------------------------
// Residual + LayerNorm over D=256: one WAVE per row, shuffle reduce, no LDS.
// 256 threads = 4 rows per block. grid = NTOK/4.
// ---------------------------------------------------------------------------
__global__ __launch_bounds__(256)
void res_ln(const float* __restrict__ res, const float* __restrict__ proj,
            const float* __restrict__ g, const float* __restrict__ be,
            float* __restrict__ out, __hip_bfloat16* __restrict__ outb, int mode) {
    const int wave = threadIdx.x >> 6, lane = threadIdx.x & 63;
    const int r = blockIdx.x * 4 + wave;
    int t;
    if (mode == 0) t = r;
    else if (mode == 1) { int q = r / 136, m = r % 136; t = m * 100 + q; }
    else { int q = r / 136, rem = r % 136; int b = rem / 17, p = rem % 17; t = b * 1700 + q * 17 + p; }
    const int c4 = lane * 4;
    float4 a = *(const float4*)&res[(size_t)r * 256 + c4];
    float4 p = *(const float4*)&proj[(size_t)t * 256 + c4];
    float v[4] = {a.x + p.x, a.y + p.y, a.z + p.z, a.w + p.w};
    float s = v[0] + v[1] + v[2] + v[3];
#pragma unroll
    for (int off = 32; off > 0; off >>= 1) s += __shfl_xor(s, off);
    float mean = s * (1.f / 256.f);
    float d[4], ss = 0.f;
#pragma unroll
    for (int i = 0; i < 4; ++i) { d[i] = v[i] - mean; ss += d[i] * d[i]; }
#pragma unroll
    for (int off = 32; off > 0; off >>= 1) ss += __shfl_xor(ss, off);
    float rs = rsqrtf(ss * (1.f / 256.f) + 1e-5f);
    float4 gv = *(const float4*)&g[c4];
    float4 bv = *(const float4*)&be[c4];
    float o0 = d[0] * rs * gv.x + bv.x;
    float o1 = d[1] * rs * gv.y + bv.y;
    float o2 = d[2] * rs * gv.z + bv.z;
    float o3 = d[3] * rs * gv.w + bv.w;
    *(float4*)&out[(size_t)r * 256 + c4] = make_float4(o0, o1, o2, o3);
    if (outb) {
        bf16x4s ob = {f2bs(o0), f2bs(o1), f2bs(o2), f2bs(o3)};
        *(bf16x4s*)&outb[(size_t)r * 256 + c4] = ob;
    }
}

// ---------------------------------------------------------------------------
extern "C" void kernel_launch(void* const* d_in, const int* in_sizes, int n_in,
                              void* d_out, int out_size, void* d_ws, size_t ws_size,
                              hipStream_t stream) {
    const float* tgt    = (const float*)d_in[0];
    const float* qpos   = (const float*)d_in[1];
    const float* ref    = (const float*)d_in[2];
    const float* memory = (const float*)d_in[3];
    const float* w_in_w = (const float*)d_in[4];
    const float* b_in_w = (const float*)d_in[5];
    const float* w_out_w= (const float*)d_in[6];
    const float* b_out_w= (const float*)d_in[7];
    const float* w_in_a = (const float*)d_in[8];
    const float* b_in_a = (const float*)d_in[9];
    const float* w_out_a= (const float*)d_in[10];
    const float* b_out_a= (const float*)d_in[11];
    const float* w_off  = (const float*)d_in[12];
    const float* b_off  = (const float*)d_in[13];
    const float* w_aw   = (const float*)d_in[14];
    const float* b_aw   = (const float*)d_in[15];
    const float* w_val  = (const float*)d_in[16];
    const float* b_val  = (const float*)d_in[17];
    const float* w_oc   = (const float*)d_in[18];
    const float* b_oc   = (const float*)d_in[19];
    const float* g_w    = (const float*)d_in[20];
    const float* be_w   = (const float*)d_in[21];
    const float* g_a    = (const float*)d_in[22];
    const float* be_a   = (const float*)d_in[23];
    const float* g1     = (const float*)d_in[24];
    const float* be1    = (const float*)d_in[25];
    const float* g2     = (const float*)d_in[26];
    const float* be2    = (const float*)d_in[27];
    const float* w1     = (const float*)d_in[28];
    const float* b1     = (const float*)d_in[29];
    const float* w2     = (const float*)d_in[30];
    const float* b2     = (const float*)d_in[31];

    float* X  = (float*)d_out;                       // persistent x, 13600x256 fp32
    float* ws = (float*)d_ws;
    float* R1 = ws;                                  // 23,046,144 f (qkv fp32 / value bf16 / H bf16)
    float* R2 = R1 + (size_t)MTOK * 256;             //  3,481,600 f
    float* R3 = R2 + (size_t)NTOK * 256;             //  1,740,800 f (bf16 attn/deform outs)
    float* R6 = R3 + (size_t)NTOK * 128;             //  1,740,800 f (raw attn weights fp32)
    float* QBF= R6 + (size_t)NTOK * 128;             //  1,740,800 f (bf16 GEMM A input)
    float* WBF= QBF+ (size_t)NTOK * 128;             //    638,976 f (packed bf16 weights)

    __hip_bfloat16* R3b = (__hip_bfloat16*)R3;
    __hip_bfloat16* Qb  = (__hip_bfloat16*)QBF;
    __hip_bfloat16* Wb  = (__hip_bfloat16*)WBF;
    __hip_bfloat16* Hb  = (__hip_bfloat16*)R1;       // ffn hidden alias (phase 4)
    __hip_bfloat16* Vb  = (__hip_bfloat16*)R1;       // bf16 value alias (phase 3)

    __hip_bfloat16* w_in_w_b  = Wb;                  // 768x256
    __hip_bfloat16* w_out_w_b = Wb +  196608;        // 256x256
    __hip_bfloat16* w_in_a_b  = Wb +  262144;        // 768x256
    __hip_bfloat16* w_out_a_b = Wb +  458752;        // 256x256
    __hip_bfloat16* w_off_b   = Wb +  524288;        // 256x256
    __hip_bfloat16* w_aw_b    = Wb +  589824;        // 128x256
    __hip_bfloat16* w_val_b   = Wb +  622592;        // 256x256
    __hip_bfloat16* w_oc_b    = Wb +  688128;        // 256x256
    __hip_bfloat16* w1_b      = Wb +  753664;        // 1024x256
    __hip_bfloat16* w2_b      = Wb + 1015808;        // 256x1024

    cvt_weights<<<4992, 256, 0, stream>>>(w_in_w, w_out_w, w_in_a, w_out_a, w_off,
                                          w_aw, w_val, w_oc, w1, w2, Wb);

    auto gemm = [&](const __hip_bfloat16* A, const __hip_bfloat16* W, const float* b,
                    float* C, int M, int N, int K, int ldc, int col0) {
        dim3 grid(N / 128, (M + 127) / 128);
        gemm_mfma<false, false, false><<<grid, 256, 0, stream>>>(A, W, b, C, M, N, K, ldc, col0);
    };
    auto gemm_a32 = [&](const float* A, const __hip_bfloat16* W, const float* b,
                        float* C, int M, int N, int K, int ldc, int col0) {
        dim3 grid(N / 128, (M + 127) / 128);
        gemm_mfma<false, false, true><<<grid, 256, 0, stream>>>(A, W, b, C, M, N, K, ldc, col0);
    };

    // ---- Phase 1: group self-attention (S=17) ----
    gather_rows_b<<<NTOK, 256, 0, stream>>>(tgt, qpos, Qb, 0);
    gemm(Qb, w_in_w_b, b_in_w, R1, NTOK, 512, 256, 768, 0);
    gemm_a32(tgt, w_in_w_b + 512 * 256, b_in_w + 512, R1, NTOK, 256, 256, 768, 512);
    attn17<<<dim3(800, 8), 256, 0, stream>>>(R1, R3b);
    gemm((const __hip_bfloat16*)R3b, w_out_w_b, b_out_w, R2, NTOK, 256, 256, 256, 0);
    res_ln<<<NTOK / 4, 256, 0, stream>>>(tgt, R2, g_w, be_w, X, nullptr, 0);

    // ---- Phase 2: query self-attention (S=100) ----
    gather_rows_b<<<NTOK, 256, 0, stream>>>(X, nullptr, Qb, 1);
    gemm(Qb, w_in_a_b, b_in_a, R1, NTOK, 768, 256, 768, 0);
    attn100<<<dim3(136, 8), 128, 0, stream>>>(R1, R3b);
    gemm((const __hip_bfloat16*)R3b, w_out_a_b, b_out_a, R2, NTOK, 256, 256, 256, 0);
    res_ln<<<NTOK / 4, 256, 0, stream>>>(X, R2, g_a, be_a, X, nullptr, 1);

    // ---- Phase 3: deformable attention ----
    {   // value projection -> bf16 output
        dim3 grid(256 / 128, (MTOK + 127) / 128);
        gemm_mfma<false, true, true><<<grid, 256, 0, stream>>>(memory, w_val_b, b_val, Vb,
                                                               MTOK, 256, 256, 256, 0);
    }
    gather_rows_b<<<NTOK, 256, 0, stream>>>(X, qpos, Qb, 2);
    gemm(Qb, w_off_b, b_off, R2, NTOK, 256, 256, 256, 0);
    gemm(Qb, w_aw_b, b_aw, R6, NTOK, 128, 256, 128, 0);
    deform_sample<<<NTOK / TPB, 256, 0, stream>>>(Vb, R2, R6, ref, R3b);
    gemm((const __hip_bfloat16*)R3b, w_oc_b, b_oc, R2, NTOK, 256, 256, 256, 0);
    res_ln<<<NTOK / 4, 256, 0, stream>>>(X, R2, g1, be1, X, Qb, 2);

    // ---- Phase 4: FFN ----
    {
        dim3 grid(DFFd / 128, (NTOK + 127) / 128);
        gemm_mfma<true, true, false><<<grid, 256, 0, stream>>>(Qb, w1_b, b1, Hb,
                                                               NTOK, DFFd, 256, DFFd, 0);
    }
    gemm((const __hip_bfloat16*)Hb, w2_b, b2, R2, NTOK, 256, 1024, 256, 0);
    res_ln<<<NTOK / 4, 256, 0, stream>>>(X, R2, g2, be2, X, nullptr, 0);
}